// Round 4
// baseline (359.633 us; speedup 1.0000x reference)
//
#include <hip/hip_runtime.h>
#include <hip/hip_fp16.h>
#include <math.h>

#define L 4096
#define CDIM 256
#define DIN 512
#define DSTATE 16
#define DTR 16
#define BATCH 4

using f32x4  = __attribute__((ext_vector_type(4))) float;
using f16x8  = __attribute__((ext_vector_type(8))) _Float16;

#define LOG2E 1.44269504088896f

#if __has_builtin(__builtin_amdgcn_exp2f)
#define EXP2(x) __builtin_amdgcn_exp2f(x)
#else
#define EXP2(x) __expf((x) * 0.69314718056f)
#endif

__device__ __forceinline__ float silu_f(float x) {
    return __fdividef(x, 1.f + __expf(-x));
}
__device__ __forceinline__ float softplus_fast(float x) {
    return (x > 20.f) ? x : __logf(1.f + __expf(x));
}
__device__ __forceinline__ unsigned pk2h(float a, float b) {
    __half2 h = __floats2half2_rn(a, b);
    return *reinterpret_cast<unsigned*>(&h);
}

#define LDK 40

// ================= fp16 MFMA GEMM: 64-row tiles, double-buffered single-barrier ====
// (Round-0 schedule: measured-good. Do not re-introduce lgkm-only barrier.)
enum { HEPI_H16 = 0, HEPI_UZ = 1, HEPI_F32 = 2, HEPI_D34 = 3 };
template<int EPI, bool A_F32KM, int NT>
__global__ __launch_bounds__(256)
void hgemm(const float* __restrict__ Af0, const float* __restrict__ Af1,
           const __half* __restrict__ Ah_g, const __half* __restrict__ Bh_g,
           const float* __restrict__ bias,
           float* __restrict__ O0, __half* __restrict__ Oh0, __half* __restrict__ Oh1,
           float* __restrict__ Ob, float* __restrict__ Oc,
           int M, int N, int K, int kSplit, long strideAb, int nBlk)
{
    constexpr int BM = 64, MT = 2;
    constexpr int BN = 2 * NT * 16;
    constexpr int BSEG = BN / 64;
    __shared__ __align__(16) _Float16 Ah[2][BM][LDK];
    __shared__ __align__(16) _Float16 Bh[2][BN][LDK];
    const int mBlk = M / BM;
    // XCD-sticky swizzle: n-blocks of one (b,m) A-tile share bid%8 -> same XCD L2
    const int bid = blockIdx.x;
    const int r = bid & 7, q = bid >> 3;
    const int ni = q % nBlk;
    const int mg = (q / nBlk) * 8 + r;
    const int b = mg / mBlk, m_idx = mg - b * mBlk;
    const int n0 = ni * BN, m0 = m_idx * BM;
    const int tid  = threadIdx.x;
    const int lane = tid & 63;
    const int w    = tid >> 6;
    const int wr   = w >> 1, wc = w & 1;
    const int lrow = lane & 15;
    const int loct = lane >> 4;

    f32x4 acc[MT][NT];
    #pragma unroll
    for (int i = 0; i < MT; ++i)
        #pragma unroll
        for (int j = 0; j < NT; ++j)
            acc[i][j] = (f32x4){0.f, 0.f, 0.f, 0.f};

    const int sOct = tid & 3, sRow = tid >> 2;
    float va[8];
    uint4 pa, pb[BSEG];

    auto loadA = [&](int kk) {
        if (A_F32KM) {
            int m = tid & 63, ks = tid >> 6;
            #pragma unroll
            for (int j = 0; j < 8; ++j) {
                int kg = kk + ks * 8 + j;
                const float* Ap; int kl;
                if (kg < kSplit) { Ap = Af0; kl = kg; } else { Ap = Af1; kl = kg - kSplit; }
                va[j] = Ap[(long)b * strideAb + (long)kl * M + m0 + m];
            }
        } else {
            pa = *(const uint4*)(Ah_g + (long)b * strideAb +
                                 (long)(m0 + sRow) * K + kk + sOct * 8);
        }
    };
    auto loadB = [&](int kk) {
        #pragma unroll
        for (int p = 0; p < BSEG; ++p) {
            int ng = n0 + sRow + p * 64;
            if (EPI == HEPI_D34 && ng >= N)
                pb[p] = make_uint4(0, 0, 0, 0);
            else
                pb[p] = *(const uint4*)(Bh_g + (long)ng * K + kk + sOct * 8);
        }
    };
    auto storeAB = [&](int buf) {
        if (A_F32KM) {
            int m = tid & 63, ks = tid >> 6;
            uint4 h;
            h.x = pk2h(va[0], va[1]);
            h.y = pk2h(va[2], va[3]);
            h.z = pk2h(va[4], va[5]);
            h.w = pk2h(va[6], va[7]);
            *(uint4*)&Ah[buf][m][ks * 8] = h;
        } else {
            *(uint4*)&Ah[buf][sRow][sOct * 8] = pa;
        }
        #pragma unroll
        for (int p = 0; p < BSEG; ++p)
            *(uint4*)&Bh[buf][sRow + p * 64][sOct * 8] = pb[p];
    };

    loadA(0); loadB(0);
    storeAB(0);
    __syncthreads();
    int cur = 0;
    for (int kk = 0; kk < K; kk += 32) {
        const bool more = (kk + 32 < K);
        if (more) { loadA(kk + 32); loadB(kk + 32); }
        f16x8 bh[NT];
        #pragma unroll
        for (int nt = 0; nt < NT; ++nt)
            bh[nt] = *(const f16x8*)&Bh[cur][wc*NT*16 + nt*16 + lrow][loct*8];
        #pragma unroll
        for (int mt = 0; mt < MT; ++mt) {
            f16x8 ah = *(const f16x8*)&Ah[cur][wr*MT*16 + mt*16 + lrow][loct*8];
            #pragma unroll
            for (int nt = 0; nt < NT; ++nt)
                acc[mt][nt] = __builtin_amdgcn_mfma_f32_16x16x32_f16(ah, bh[nt], acc[mt][nt], 0, 0, 0);
        }
        if (more) {
            storeAB(cur ^ 1);
            __syncthreads();
            cur ^= 1;
        }
    }
    #pragma unroll
    for (int mt = 0; mt < MT; ++mt) {
        #pragma unroll
        for (int r4 = 0; r4 < 4; ++r4) {
            int m = m0 + wr*MT*16 + mt * 16 + loct * 4 + r4;
            long rowb = (long)b * M + m;
            #pragma unroll
            for (int nt = 0; nt < NT; ++nt) {
                int n = n0 + wc*NT*16 + nt * 16 + lrow;
                float v = acc[mt][nt][r4];
                if (EPI == HEPI_H16) {
                    Oh0[rowb * N + n] = __float2half(v);
                } else if (EPI == HEPI_UZ) {
                    float vb = v + bias[n];          // fused W_in @ b_proj bias
                    if (n < DIN) Oh0[rowb * DIN + n] = __float2half(vb);
                    else         Oh1[rowb * DIN + (n - DIN)] = __float2half(vb);
                } else if (EPI == HEPI_D34) {
                    // rank-16 dbc outputs: dt raw (delta folded into scans), Bm, Cm
                    if (n < DTR)           O0[rowb * DTR + n] = v;
                    else if (n < 2 * DTR)  Ob[rowb * 16 + (n - DTR)] = v;
                    else if (n < 48)       Oc[rowb * 16 + (n - 32)] = v;
                } else {
                    O0[rowb * N + n] = v;
                }
            }
        }
    }
}

// ---------------- weight prep ----------------
// wpt  = Wp^T as fp16 (512x256, K-major for the weight-product GEMM)
// winh = Win fp16 (1024x256)
// woh  = Wout fp16, wch = Wx fp16 (48x512)
// bf   = Win @ b_proj (fp32, 1024) -- fused GEMM12 bias
#define SZ_WPT 131072
#define SZ_WIN 262144
#define SZ_WO  131072
#define SZ_WC  24576
#define SZ_BF  1024
__global__ __launch_bounds__(256)
void pack_all(const float* __restrict__ Wp, const float* __restrict__ Win,
              const float* __restrict__ Wout, const float* __restrict__ Wx,
              const float* __restrict__ bp,
              __half* __restrict__ wpt, __half* __restrict__ winh,
              __half* __restrict__ woh, __half* __restrict__ wch,
              float* __restrict__ bf)
{
    int i = blockIdx.x * 256 + threadIdx.x;
    if (i < SZ_WPT) {   // transpose: wpt[e][c] = Wp[c][e], e<512, c<256
        wpt[i] = __float2half(Wp[(i & 255) * 512 + (i >> 8)]);
        return;
    }
    i -= SZ_WPT;
    if (i < SZ_WIN) { winh[i] = __float2half(Win[i]); return; }
    i -= SZ_WIN;
    if (i < SZ_WO) { woh[i] = __float2half(Wout[i]); return; }
    i -= SZ_WO;
    if (i < SZ_WC) { wch[i] = __float2half(Wx[i]); return; }
    i -= SZ_WC;
    if (i < SZ_BF) {
        float acc = 0.f;
        for (int c = 0; c < CDIM; ++c)
            acc = fmaf(Win[i * CDIM + c], bp[c], acc);
        bf[i] = acc;
    }
}

// ---------------- depthwise causal conv (k=4) + silu ---------
__global__ __launch_bounds__(256)
void conv_silu_kernel(const __half* __restrict__ u_pre, const float* __restrict__ cw,
                      const float* __restrict__ cb, __half* __restrict__ u)
{
    long idx = (long)blockIdx.x * blockDim.x + threadIdx.x;
    int d = (int)(idx % DIN);
    long bl = idx / DIN;
    int l = (int)(bl % L);
    long brow = bl - l;
    float v = cb[d];
    #pragma unroll
    for (int j = 0; j < 4; ++j) {
        int li = l - 3 + j;
        if (li >= 0) v += __half2float(u_pre[(brow + li) * DIN + d]) * cw[d * 4 + j];
    }
    u[idx] = __float2half(silu_f(v));
}

// ---------------- chunked parallel selective scan, d-per-lane ----------------
// Issue-bound (VALUBusy ~65%, 0 bank conflicts): optimize by DELETING instructions.
// 1) A_log = log(arange(1..16)) in this model => A[s] = (s+1)*A[0]; then
//    a_s = r^(s+1) with r = exp2(dlt*Arow0): 1 trans + 15 muls instead of 16 trans.
//    Guarded per-thread (generic fallback loop kept for arbitrary A).
// 2) phase1's P[s] = prod_t a_s(t) = exp2(Arow[s] * sum_t dlt): one scalar dsum,
//    P computed once at the end (deletes 16 FMAs/step).
#define NC 128
#define LC (L / NC)

// depth-4 power tree: av[s] = r^(s+1), 15 muls
#define POWERS16(r, av) \
    { av[0]=(r); av[1]=av[0]*av[0]; av[2]=av[1]*av[0]; av[3]=av[1]*av[1]; \
      av[4]=av[3]*av[0]; av[5]=av[3]*av[1]; av[6]=av[3]*av[2]; av[7]=av[3]*av[3]; \
      av[8]=av[7]*av[0]; av[9]=av[7]*av[1]; av[10]=av[7]*av[2]; av[11]=av[7]*av[3]; \
      av[12]=av[7]*av[4]; av[13]=av[7]*av[5]; av[14]=av[7]*av[6]; av[15]=av[7]*av[7]; }

__global__ __launch_bounds__(256)
void scan_phase1(const float* __restrict__ dtA, const __half* __restrict__ u,
                 const float* __restrict__ Bm, const float* __restrict__ A_log,
                 const float* __restrict__ Wdt, const float* __restrict__ bdt,
                 float* __restrict__ AX)
{
    __shared__ float sB[LC][DSTATE];
    __shared__ float sDt[LC][DTR];
    __shared__ __half sU[LC][256];
    const int gd = blockIdx.x & 1;
    const int c  = (blockIdx.x >> 1) & (NC - 1);
    const int b  = blockIdx.x >> 8;
    const int tid = threadIdx.x;
    const int d  = gd * 256 + tid;
    const int t0 = c * LC;
    float Arow[DSTATE];
    #pragma unroll
    for (int q = 0; q < 4; ++q) {
        float4 v = *(const float4*)&A_log[d * DSTATE + q * 4];
        Arow[q * 4 + 0] = -__expf(v.x) * LOG2E;
        Arow[q * 4 + 1] = -__expf(v.y) * LOG2E;
        Arow[q * 4 + 2] = -__expf(v.z) * LOG2E;
        Arow[q * 4 + 3] = -__expf(v.w) * LOG2E;
    }
    bool intA = true;
    #pragma unroll
    for (int s = 1; s < DSTATE; ++s)
        intA = intA && (fabsf(Arow[s] - (float)(s + 1) * Arow[0]) <= 1e-3f * (float)(s + 1));
    const float A0L = Arow[0];
    const float4 W0 = *(const float4*)&Wdt[d * DTR + 0];
    const float4 W1 = *(const float4*)&Wdt[d * DTR + 4];
    const float4 W2 = *(const float4*)&Wdt[d * DTR + 8];
    const float4 W3 = *(const float4*)&Wdt[d * DTR + 12];
    const float bd = bdt[d];
    {
        const __half* ub = u + ((long)b * L + t0) * DIN + gd * 256;
        #pragma unroll
        for (int j = 0; j < 4; ++j) {
            int i = tid + j * 256;
            int t = i >> 5, col = (i & 31) * 8;
            *(float4*)&sU[t][col] = *(const float4*)&ub[(long)t * DIN + col];
        }
        if (tid < 128) {
            const float* Bb = Bm  + ((long)b * L + t0) * DSTATE;
            const float* Db = dtA + ((long)b * L + t0) * DTR;
            *(float4*)&((float*)sB)[tid * 4]  = *(const float4*)&Bb[tid * 4];
            *(float4*)&((float*)sDt)[tid * 4] = *(const float4*)&Db[tid * 4];
        }
    }
    __syncthreads();
    float X[DSTATE];
    #pragma unroll
    for (int s = 0; s < DSTATE; ++s) X[s] = 0.f;
    float dsum = 0.f;

#define P1_HEAD \
        float4 q0 = *(const float4*)&sDt[t][0]; \
        float4 q1 = *(const float4*)&sDt[t][4]; \
        float4 q2 = *(const float4*)&sDt[t][8]; \
        float4 q3 = *(const float4*)&sDt[t][12]; \
        float dp0 = fmaf(q0.x, W0.x, fmaf(q0.y, W0.y, fmaf(q0.z, W0.z, q0.w * W0.w))); \
        float dp1 = fmaf(q1.x, W1.x, fmaf(q1.y, W1.y, fmaf(q1.z, W1.z, q1.w * W1.w))); \
        float dp2 = fmaf(q2.x, W2.x, fmaf(q2.y, W2.y, fmaf(q2.z, W2.z, q2.w * W2.w))); \
        float dp3 = fmaf(q3.x, W3.x, fmaf(q3.y, W3.y, fmaf(q3.z, W3.z, q3.w * W3.w))); \
        float dlt = softplus_fast(((dp0 + dp1) + (dp2 + dp3)) + bd); \
        dsum += dlt; \
        float du = dlt * __half2float(sU[t][tid]); \
        float Brow[DSTATE]; \
        *(float4*)&Brow[0]  = *(const float4*)&sB[t][0]; \
        *(float4*)&Brow[4]  = *(const float4*)&sB[t][4]; \
        *(float4*)&Brow[8]  = *(const float4*)&sB[t][8]; \
        *(float4*)&Brow[12] = *(const float4*)&sB[t][12];

    if (intA) {
        #pragma unroll 2
        for (int t = 0; t < LC; ++t) {
            P1_HEAD
            float av[DSTATE];
            float rr = EXP2(dlt * A0L);
            POWERS16(rr, av)
            #pragma unroll
            for (int s = 0; s < DSTATE; ++s)
                X[s] = fmaf(av[s], X[s], du * Brow[s]);
        }
    } else {
        #pragma unroll 2
        for (int t = 0; t < LC; ++t) {
            P1_HEAD
            #pragma unroll
            for (int s = 0; s < DSTATE; ++s) {
                float a = EXP2(dlt * Arow[s]);
                X[s] = fmaf(a, X[s], du * Brow[s]);
            }
        }
    }
#undef P1_HEAD
    float P[DSTATE];
    #pragma unroll
    for (int s = 0; s < DSTATE; ++s) P[s] = EXP2(dsum * Arow[s]);
    long o2 = ((((long)b * NC + c) * DIN + d) * DSTATE) * 2;
    #pragma unroll
    for (int q = 0; q < 8; ++q)
        *(float4*)&AX[o2 + q * 4] =
            make_float4(P[2*q], X[2*q], P[2*q+1], X[2*q+1]);
}

// cross-chunk scan: 32768 independent series; pure-ILP kernel.
__global__ __launch_bounds__(256)
void scan_phase2(const float* __restrict__ AX, float* __restrict__ Hout)
{
    int lane = blockIdx.x * 256 + threadIdx.x;   // 32768 total
    int b = lane >> 13;
    int rem = lane & 8191;
    const long cs = (long)DIN * DSTATE;
    const long base = (long)b * NC * cs + rem;
    float h = 0.f;
    float2 c0, c1, c2, c3, n0, n1, n2, n3;
    auto ld = [&](int c) -> float2 {
        return *(const float2*)&AX[2 * (base + (long)c * cs)];
    };
    c0 = ld(0); c1 = ld(1); c2 = ld(2); c3 = ld(3);
    n0 = ld(4); n1 = ld(5); n2 = ld(6); n3 = ld(7);
    for (int c = 0; c < NC; c += 4) {
        Hout[base + (long)(c+0) * cs] = h; h = fmaf(c0.x, h, c0.y);
        Hout[base + (long)(c+1) * cs] = h; h = fmaf(c1.x, h, c1.y);
        Hout[base + (long)(c+2) * cs] = h; h = fmaf(c2.x, h, c2.y);
        Hout[base + (long)(c+3) * cs] = h; h = fmaf(c3.x, h, c3.y);
        c0 = n0; c1 = n1; c2 = n2; c3 = n3;
        if (c + 8 < NC) { n0 = ld(c+8); n1 = ld(c+9); n2 = ld(c+10); n3 = ld(c+11); }
    }
}

__global__ __launch_bounds__(256)
void scan_phase3(const float* __restrict__ dtA, const __half* __restrict__ u,
                 const float* __restrict__ Bm, const float* __restrict__ Cm,
                 const __half* __restrict__ z, const float* __restrict__ A_log,
                 const float* __restrict__ Wdt, const float* __restrict__ bdt,
                 const float* __restrict__ Dp, const float* __restrict__ Hinit,
                 __half* __restrict__ y2h)
{
    __shared__ float sB[LC][DSTATE], sC[LC][DSTATE];
    __shared__ float sDt[LC][DTR];
    __shared__ __half sU[LC][256];
    __shared__ __half sZ[LC][256];
    const int gd = blockIdx.x & 1;
    const int c  = (blockIdx.x >> 1) & (NC - 1);
    const int b  = blockIdx.x >> 8;
    const int tid = threadIdx.x;
    const int d  = gd * 256 + tid;
    const int t0 = c * LC;
    float Arow[DSTATE];
    #pragma unroll
    for (int q = 0; q < 4; ++q) {
        float4 v = *(const float4*)&A_log[d * DSTATE + q * 4];
        Arow[q * 4 + 0] = -__expf(v.x) * LOG2E;
        Arow[q * 4 + 1] = -__expf(v.y) * LOG2E;
        Arow[q * 4 + 2] = -__expf(v.z) * LOG2E;
        Arow[q * 4 + 3] = -__expf(v.w) * LOG2E;
    }
    bool intA = true;
    #pragma unroll
    for (int s = 1; s < DSTATE; ++s)
        intA = intA && (fabsf(Arow[s] - (float)(s + 1) * Arow[0]) <= 1e-3f * (float)(s + 1));
    const float A0L = Arow[0];
    const float4 W0 = *(const float4*)&Wdt[d * DTR + 0];
    const float4 W1 = *(const float4*)&Wdt[d * DTR + 4];
    const float4 W2 = *(const float4*)&Wdt[d * DTR + 8];
    const float4 W3 = *(const float4*)&Wdt[d * DTR + 12];
    const float bd = bdt[d];
    {
        const __half* ub = u + ((long)b * L + t0) * DIN + gd * 256;
        const __half* zb = z + ((long)b * L + t0) * DIN + gd * 256;
        #pragma unroll
        for (int j = 0; j < 4; ++j) {
            int i = tid + j * 256;
            int t = i >> 5, col = (i & 31) * 8;
            *(float4*)&sU[t][col] = *(const float4*)&ub[(long)t * DIN + col];
            *(float4*)&sZ[t][col] = *(const float4*)&zb[(long)t * DIN + col];
        }
        if (tid < 128) {
            const float* Bb = Bm  + ((long)b * L + t0) * DSTATE;
            const float* Cb = Cm  + ((long)b * L + t0) * DSTATE;
            const float* Db = dtA + ((long)b * L + t0) * DTR;
            *(float4*)&((float*)sB)[tid * 4]  = *(const float4*)&Bb[tid * 4];
            *(float4*)&((float*)sC)[tid * 4]  = *(const float4*)&Cb[tid * 4];
            *(float4*)&((float*)sDt)[tid * 4] = *(const float4*)&Db[tid * 4];
        }
    }
    float h[DSTATE];
    {
        long o = (((long)b * NC + c) * DIN + d) * DSTATE;
        #pragma unroll
        for (int q = 0; q < 4; ++q) {
            float4 v = *(const float4*)&Hinit[o + q * 4];
            h[q * 4 + 0] = v.x; h[q * 4 + 1] = v.y;
            h[q * 4 + 2] = v.z; h[q * 4 + 3] = v.w;
        }
    }
    const float Dval = Dp[d];
    const long gbase = ((long)b * L + t0) * DIN + d;
    __syncthreads();

#define P3_HEAD \
        float4 q0 = *(const float4*)&sDt[t][0]; \
        float4 q1 = *(const float4*)&sDt[t][4]; \
        float4 q2 = *(const float4*)&sDt[t][8]; \
        float4 q3 = *(const float4*)&sDt[t][12]; \
        float dp0 = fmaf(q0.x, W0.x, fmaf(q0.y, W0.y, fmaf(q0.z, W0.z, q0.w * W0.w))); \
        float dp1 = fmaf(q1.x, W1.x, fmaf(q1.y, W1.y, fmaf(q1.z, W1.z, q1.w * W1.w))); \
        float dp2 = fmaf(q2.x, W2.x, fmaf(q2.y, W2.y, fmaf(q2.z, W2.z, q2.w * W2.w))); \
        float dp3 = fmaf(q3.x, W3.x, fmaf(q3.y, W3.y, fmaf(q3.z, W3.z, q3.w * W3.w))); \
        float dlt = softplus_fast(((dp0 + dp1) + (dp2 + dp3)) + bd); \
        float uu = __half2float(sU[t][tid]); \
        float zz = __half2float(sZ[t][tid]); \
        float du = dlt * uu; \
        float Brow[DSTATE], Crow[DSTATE]; \
        *(float4*)&Brow[0]  = *(const float4*)&sB[t][0]; \
        *(float4*)&Brow[4]  = *(const float4*)&sB[t][4]; \
        *(float4*)&Brow[8]  = *(const float4*)&sB[t][8]; \
        *(float4*)&Brow[12] = *(const float4*)&sB[t][12]; \
        *(float4*)&Crow[0]  = *(const float4*)&sC[t][0]; \
        *(float4*)&Crow[4]  = *(const float4*)&sC[t][4]; \
        *(float4*)&Crow[8]  = *(const float4*)&sC[t][8]; \
        *(float4*)&Crow[12] = *(const float4*)&sC[t][12];

#define P3_TAIL(AV) \
        float y0 = 0.f, y1 = 0.f, y2 = 0.f, y3 = 0.f; \
        _Pragma("unroll") \
        for (int s = 0; s < DSTATE; s += 4) { \
            h[s+0] = fmaf(h[s+0], AV(s+0), du * Brow[s+0]); \
            h[s+1] = fmaf(h[s+1], AV(s+1), du * Brow[s+1]); \
            h[s+2] = fmaf(h[s+2], AV(s+2), du * Brow[s+2]); \
            h[s+3] = fmaf(h[s+3], AV(s+3), du * Brow[s+3]); \
            y0 = fmaf(h[s+0], Crow[s+0], y0); \
            y1 = fmaf(h[s+1], Crow[s+1], y1); \
            y2 = fmaf(h[s+2], Crow[s+2], y2); \
            y3 = fmaf(h[s+3], Crow[s+3], y3); \
        } \
        float y = (y0 + y1) + (y2 + y3); \
        y2h[gbase + t * DIN] = __float2half((y + uu * Dval) * silu_f(zz));

    if (intA) {
        #pragma unroll 2
        for (int t = 0; t < LC; ++t) {
            P3_HEAD
            float av[DSTATE];
            float rr = EXP2(dlt * A0L);
            POWERS16(rr, av)
            #define AVF(s) av[s]
            P3_TAIL(AVF)
            #undef AVF
        }
    } else {
        #pragma unroll 2
        for (int t = 0; t < LC; ++t) {
            P3_HEAD
            #define AVG(s) EXP2(dlt * Arow[s])
            P3_TAIL(AVG)
            #undef AVG
        }
    }
#undef P3_HEAD
#undef P3_TAIL
}

// ---------------- LayerNorm over C + transpose to (B,C,L) ----------------
__global__ __launch_bounds__(256)
void ln_kernel(const float* __restrict__ X, const float* __restrict__ gamma,
               const float* __restrict__ beta, float* __restrict__ out)
{
    __shared__ float tile[32][257];
    __shared__ float sMu[32], sRs[32];
    const int l0 = blockIdx.x * 32;
    const int b  = blockIdx.y;
    const int tid = threadIdx.x;
    for (int i = tid; i < 32 * 256; i += 256) {
        int l = i >> 8, c = i & 255;
        tile[l][c] = X[((long)b * L + l0 + l) * CDIM + c];
    }
    __syncthreads();
    {
        int l = tid >> 3, sub = tid & 7;
        float s1 = 0.f, s2 = 0.f;
        for (int c = sub * 32; c < sub * 32 + 32; ++c) {
            float v = tile[l][c];
            s1 += v; s2 += v * v;
        }
        s1 += __shfl_xor(s1, 1); s2 += __shfl_xor(s2, 1);
        s1 += __shfl_xor(s1, 2); s2 += __shfl_xor(s2, 2);
        s1 += __shfl_xor(s1, 4); s2 += __shfl_xor(s2, 4);
        if (sub == 0) {
            float mu = s1 * (1.f / 256.f);
            float var = s2 * (1.f / 256.f) - mu * mu;
            sMu[l] = mu;
            sRs[l] = rsqrtf(var + 1e-5f);
        }
    }
    __syncthreads();
    for (int i = tid; i < 32 * 256; i += 256) {
        int ll = i & 31, c = i >> 5;
        float v = (tile[ll][c] - sMu[ll]) * sRs[ll] * gamma[c] + beta[c];
        out[((long)b * CDIM + c) * L + l0 + ll] = v;
    }
}

extern "C" void kernel_launch(void* const* d_in, const int* in_sizes, int n_in,
                              void* d_out, int out_size, void* d_ws, size_t ws_size,
                              hipStream_t stream)
{
    const float* sp   = (const float*)d_in[0];
    const float* fq   = (const float*)d_in[1];
    const float* Wp   = (const float*)d_in[2];
    const float* bp   = (const float*)d_in[3];
    const float* Win  = (const float*)d_in[4];
    const float* cw   = (const float*)d_in[5];
    const float* cb   = (const float*)d_in[6];
    const float* Wx   = (const float*)d_in[7];
    const float* Wdt  = (const float*)d_in[8];
    const float* bdt  = (const float*)d_in[9];
    const float* Alog = (const float*)d_in[10];
    const float* Dp   = (const float*)d_in[11];
    const float* Wout = (const float*)d_in[12];
    const float* gam  = (const float*)d_in[13];
    const float* bet  = (const float*)d_in[14];
    float* out = (float*)d_out;
    float* ws  = (float*)d_ws;

    const size_t NLD = (size_t)BATCH * L * DIN;   // 8.39M
    const size_t NLC = (size_t)BATCH * L * CDIM;  // 4.19M

    size_t off = 0;
    __half* u16   = (__half*)(ws + off); off += NLD / 2;  // pre-conv u
    __half* u16c  = (__half*)(ws + off); off += NLD / 2;  // post-conv silu(u)
    __half* z16   = (__half*)(ws + off); off += NLD / 2;
    __half* y16   = (__half*)(ws + off); off += NLD / 2;
    float*  xmix  = ws + off; off += NLC;
    float*  dtA   = ws + off; off += (size_t)BATCH * L * DTR;
    __half* wpt   = (__half*)(ws + off); off += SZ_WPT / 2;
    __half* winh  = (__half*)(ws + off); off += SZ_WIN / 2;
    __half* woh   = (__half*)(ws + off); off += SZ_WO / 2;
    __half* wch   = (__half*)(ws + off); off += SZ_WC / 2;
    __half* wfh   = (__half*)(ws + off); off += (size_t)1024 * 512 / 2;  // W_f fp16
    float*  bf    = ws + off; off += SZ_BF;
    float*  Bmb   = ws + off; off += (size_t)BATCH * L * DSTATE;
    float*  Cmb   = ws + off; off += (size_t)BATCH * L * DSTATE;
    float*  AX    = ws + off; off += (size_t)BATCH * NC * DIN * DSTATE * 2;
    float*  Hout  = ws + off; off += (size_t)BATCH * NC * DIN * DSTATE;

    dim3 blk(256);
    pack_all<<<dim3((SZ_WPT + SZ_WIN + SZ_WO + SZ_WC + SZ_BF) / 256), blk, 0, stream>>>(
        Wp, Win, Wout, Wx, bp, wpt, winh, woh, wch, bf);

    // weight product: W_f[E,e] = sum_c Win[E,c] * Wp[c,e]  (1024x512, K=256)
    hgemm<HEPI_H16, false, 4><<<dim3(64), blk, 0, stream>>>(
        nullptr, nullptr, winh, wpt, nullptr, nullptr, wfh, nullptr, nullptr, nullptr,
        1024, 512, 256, 1 << 30, (long)1024 * 256, 4);

    // GEMM12 (fused GEMM1+GEMM2): xz = x_cat @ W_f^T + Win@bp -> u16 / z16
    // A = [sp|fq] fp32 K-major, K=512, N=1024
    hgemm<HEPI_UZ, true, 4><<<dim3(BATCH * (L/64) * 8), blk, 0, stream>>>(
        sp, fq, nullptr, wfh, bf, nullptr, u16, z16, nullptr, nullptr,
        L, 2 * DIN, 2 * CDIM, CDIM, (long)CDIM * L, 8);

    conv_silu_kernel<<<dim3((int)(NLD / 256)), blk, 0, stream>>>(u16, cw, cb, u16c);
    // D34 rank-16: dbc = u @ Wx^T (N=48: dt|Bm|Cm). delta folded into scans.
    hgemm<HEPI_D34, false, 2><<<dim3(BATCH * (L/64) * 1), blk, 0, stream>>>(
        nullptr, nullptr, u16c, wch, nullptr, dtA, nullptr, nullptr, Bmb, Cmb,
        L, 48, DIN, 1 << 30, (long)L * DIN, 1);

    scan_phase1<<<dim3(BATCH * NC * 2), blk, 0, stream>>>(
        dtA, u16c, Bmb, Alog, Wdt, bdt, AX);
    scan_phase2<<<dim3(BATCH * DIN * DSTATE / 256), blk, 0, stream>>>(AX, Hout);
    scan_phase3<<<dim3(BATCH * NC * 2), blk, 0, stream>>>(
        dtA, u16c, Bmb, Cmb, z16, Alog, Wdt, bdt, Dp, Hout, y16);

    // GEMM5 (fp16): x_mixed = y2 @ Wout^T
    hgemm<HEPI_F32, false, 2><<<dim3(BATCH * (L/64) * 4), blk, 0, stream>>>(
        nullptr, nullptr, y16, woh, nullptr, xmix, nullptr, nullptr, nullptr, nullptr,
        L, CDIM, DIN, 1 << 30, (long)L * DIN, 4);
    ln_kernel<<<dim3(L / 32, BATCH), blk, 0, stream>>>(xmix, gam, bet, out);
}

// Round 5
// 357.764 us; speedup vs baseline: 1.0052x; 1.0052x over previous
//
#include <hip/hip_runtime.h>
#include <hip/hip_fp16.h>
#include <math.h>

#define L 4096
#define CDIM 256
#define DIN 512
#define DSTATE 16
#define DTR 16
#define BATCH 4

using f32x4  = __attribute__((ext_vector_type(4))) float;
using f16x8  = __attribute__((ext_vector_type(8))) _Float16;

#define LOG2E 1.44269504088896f

#if __has_builtin(__builtin_amdgcn_exp2f)
#define EXP2(x) __builtin_amdgcn_exp2f(x)
#else
#define EXP2(x) __expf((x) * 0.69314718056f)
#endif

__device__ __forceinline__ float silu_f(float x) {
    return __fdividef(x, 1.f + __expf(-x));
}
__device__ __forceinline__ float softplus_fast(float x) {
    return (x > 20.f) ? x : __logf(1.f + __expf(x));
}
__device__ __forceinline__ unsigned pk2h(float a, float b) {
    __half2 h = __floats2half2_rn(a, b);
    return *reinterpret_cast<unsigned*>(&h);
}

#define LDK 40

// LESSONS (measured, do not repeat):
//  - r1: lgkm-only barrier + depth-2 reg prefetch regressed (6.6->4.4 MfmaUtil).
//  - r4: GEMM1+GEMM2 fusion neutral (stall-bound; blocks x k-iters unchanged).
//  - r4: replacing the 16 exp2 (trans pipe, hidden under VALU) with 15 serial
//    VALU muls REGRESSED the scans ~+23us. Delete VALU ops, keep trans ops.
//  - WRITE_SIZE on the first long dispatch includes harness memset traffic
//    (workspace ~0.5GB) -- artifact, ignore it there.

enum { HEPI_XP = 0, HEPI_UZ = 1, HEPI_F32 = 2, HEPI_D34 = 3 };

// ============ hgemm128: 128x128 tile, 4 waves (2x2), 64x64 per wave ============
// Same single-barrier double-buffered schedule as the proven 64-tile kernel,
// but 64 MFMA per wave per k-iter (vs 16): the ~300-400cyc load-wait+barrier
// stall per iter amortizes over 4x more matrix work (m93-style step).
template<int EPI, bool A_F32KM>
__global__ __launch_bounds__(256)
void hgemm128(const float* __restrict__ Af0, const float* __restrict__ Af1,
              const __half* __restrict__ Ah_g, const __half* __restrict__ Bh_g,
              const float* __restrict__ bias,
              float* __restrict__ O0, __half* __restrict__ Oh0, __half* __restrict__ Oh1,
              int M, int N, int K, int kSplit, long strideAb, int nBlk)
{
    constexpr int BM = 128, BN = 128, MT = 4, NT = 4;
    __shared__ __align__(16) _Float16 Ah[2][BM][LDK];
    __shared__ __align__(16) _Float16 Bh[2][BN][LDK];
    const int mBlk = M / BM;
    // XCD-sticky swizzle: n-blocks of one (b,m) A-tile share bid%8 -> same XCD L2
    const int bid = blockIdx.x;
    const int r = bid & 7, q = bid >> 3;
    const int ni = q % nBlk;
    const int mg = (q / nBlk) * 8 + r;
    const int b = mg / mBlk, m_idx = mg - b * mBlk;
    const int n0 = ni * BN, m0 = m_idx * BM;
    const int tid  = threadIdx.x;
    const int lane = tid & 63;
    const int w    = tid >> 6;
    const int wr   = w >> 1, wc = w & 1;
    const int lrow = lane & 15;
    const int loct = lane >> 4;

    f32x4 acc[MT][NT];
    #pragma unroll
    for (int i = 0; i < MT; ++i)
        #pragma unroll
        for (int j = 0; j < NT; ++j)
            acc[i][j] = (f32x4){0.f, 0.f, 0.f, 0.f};

    const int sOct = tid & 3, sRow = tid >> 2;   // 64 rows/pass, 2 passes; 4x16B per row
    float va[16];
    uint4 pa[2], pb[2];

    auto loadA = [&](int kk) {
        if (A_F32KM) {
            int m = tid & 127, kh = (tid >> 7) * 16;   // 2 k-slices of 16
            #pragma unroll
            for (int j = 0; j < 16; ++j) {
                int kg = kk + kh + j;
                const float* Ap; int kl;
                if (kg < kSplit) { Ap = Af0; kl = kg; } else { Ap = Af1; kl = kg - kSplit; }
                va[j] = Ap[(long)b * strideAb + (long)kl * M + m0 + m];
            }
        } else {
            #pragma unroll
            for (int p = 0; p < 2; ++p)
                pa[p] = *(const uint4*)(Ah_g + (long)b * strideAb +
                                        (long)(m0 + sRow + p * 64) * K + kk + sOct * 8);
        }
    };
    auto loadB = [&](int kk) {
        #pragma unroll
        for (int p = 0; p < 2; ++p)
            pb[p] = *(const uint4*)(Bh_g + (long)(n0 + sRow + p * 64) * K + kk + sOct * 8);
    };
    auto storeAB = [&](int buf) {
        if (A_F32KM) {
            int m = tid & 127, kh = (tid >> 7) * 16;
            uint4 h0, h1;
            h0.x = pk2h(va[0], va[1]);   h0.y = pk2h(va[2], va[3]);
            h0.z = pk2h(va[4], va[5]);   h0.w = pk2h(va[6], va[7]);
            h1.x = pk2h(va[8], va[9]);   h1.y = pk2h(va[10], va[11]);
            h1.z = pk2h(va[12], va[13]); h1.w = pk2h(va[14], va[15]);
            *(uint4*)&Ah[buf][m][kh]     = h0;
            *(uint4*)&Ah[buf][m][kh + 8] = h1;
        } else {
            #pragma unroll
            for (int p = 0; p < 2; ++p)
                *(uint4*)&Ah[buf][sRow + p * 64][sOct * 8] = pa[p];
        }
        #pragma unroll
        for (int p = 0; p < 2; ++p)
            *(uint4*)&Bh[buf][sRow + p * 64][sOct * 8] = pb[p];
    };

    loadA(0); loadB(0);
    storeAB(0);
    __syncthreads();
    int cur = 0;
    for (int kk = 0; kk < K; kk += 32) {
        const bool more = (kk + 32 < K);
        if (more) { loadA(kk + 32); loadB(kk + 32); }   // in flight during MFMA
        f16x8 bh[NT];
        #pragma unroll
        for (int nt = 0; nt < NT; ++nt)
            bh[nt] = *(const f16x8*)&Bh[cur][wc*64 + nt*16 + lrow][loct*8];
        #pragma unroll
        for (int mt = 0; mt < MT; ++mt) {
            f16x8 ah = *(const f16x8*)&Ah[cur][wr*64 + mt*16 + lrow][loct*8];
            #pragma unroll
            for (int nt = 0; nt < NT; ++nt)
                acc[mt][nt] = __builtin_amdgcn_mfma_f32_16x16x32_f16(ah, bh[nt], acc[mt][nt], 0, 0, 0);
        }
        if (more) {
            storeAB(cur ^ 1);
            __syncthreads();        // ONE barrier per k-iter
            cur ^= 1;
        }
    }
    // epilogue: C/D col=lane&15, row=(lane>>4)*4+reg
    #pragma unroll
    for (int mt = 0; mt < MT; ++mt) {
        #pragma unroll
        for (int r4 = 0; r4 < 4; ++r4) {
            int m = m0 + wr*64 + mt * 16 + loct * 4 + r4;
            long rowb = (long)b * M + m;
            #pragma unroll
            for (int nt = 0; nt < NT; ++nt) {
                int n = n0 + wc*64 + nt * 16 + lrow;
                float v = acc[mt][nt][r4];
                if (EPI == HEPI_XP) {
                    Oh0[rowb * N + n] = __float2half(v + bias[n]);
                } else if (EPI == HEPI_UZ) {
                    if (n < DIN) Oh0[rowb * DIN + n] = __float2half(v);
                    else         Oh1[rowb * DIN + (n - DIN)] = __float2half(v);
                } else {
                    O0[rowb * N + n] = v;
                }
            }
        }
    }
}

// ============ old 64-row-tile hgemm: kept ONLY for D34 (N=48) ============
template<int EPI, bool A_F32KM, int NT>
__global__ __launch_bounds__(256)
void hgemm(const float* __restrict__ Af0, const float* __restrict__ Af1,
           const __half* __restrict__ Ah_g, const __half* __restrict__ Bh_g,
           const float* __restrict__ bias,
           float* __restrict__ O0, __half* __restrict__ Oh0, __half* __restrict__ Oh1,
           float* __restrict__ Ob, float* __restrict__ Oc,
           int M, int N, int K, int kSplit, long strideAb, int nBlk)
{
    constexpr int BM = 64, MT = 2;
    constexpr int BN = 2 * NT * 16;
    constexpr int BSEG = BN / 64;
    __shared__ __align__(16) _Float16 Ah[2][BM][LDK];
    __shared__ __align__(16) _Float16 Bh[2][BN][LDK];
    const int mBlk = M / BM;
    const int bid = blockIdx.x;
    const int r = bid & 7, q = bid >> 3;
    const int ni = q % nBlk;
    const int mg = (q / nBlk) * 8 + r;
    const int b = mg / mBlk, m_idx = mg - b * mBlk;
    const int n0 = ni * BN, m0 = m_idx * BM;
    const int tid  = threadIdx.x;
    const int lane = tid & 63;
    const int w    = tid >> 6;
    const int wr   = w >> 1, wc = w & 1;
    const int lrow = lane & 15;
    const int loct = lane >> 4;

    f32x4 acc[MT][NT];
    #pragma unroll
    for (int i = 0; i < MT; ++i)
        #pragma unroll
        for (int j = 0; j < NT; ++j)
            acc[i][j] = (f32x4){0.f, 0.f, 0.f, 0.f};

    const int sOct = tid & 3, sRow = tid >> 2;
    uint4 pa, pb[BSEG];

    auto loadA = [&](int kk) {
        pa = *(const uint4*)(Ah_g + (long)b * strideAb +
                             (long)(m0 + sRow) * K + kk + sOct * 8);
    };
    auto loadB = [&](int kk) {
        #pragma unroll
        for (int p = 0; p < BSEG; ++p) {
            int ng = n0 + sRow + p * 64;
            if (EPI == HEPI_D34 && ng >= N)
                pb[p] = make_uint4(0, 0, 0, 0);
            else
                pb[p] = *(const uint4*)(Bh_g + (long)ng * K + kk + sOct * 8);
        }
    };
    auto storeAB = [&](int buf) {
        *(uint4*)&Ah[buf][sRow][sOct * 8] = pa;
        #pragma unroll
        for (int p = 0; p < BSEG; ++p)
            *(uint4*)&Bh[buf][sRow + p * 64][sOct * 8] = pb[p];
    };

    loadA(0); loadB(0);
    storeAB(0);
    __syncthreads();
    int cur = 0;
    for (int kk = 0; kk < K; kk += 32) {
        const bool more = (kk + 32 < K);
        if (more) { loadA(kk + 32); loadB(kk + 32); }
        f16x8 bh[NT];
        #pragma unroll
        for (int nt = 0; nt < NT; ++nt)
            bh[nt] = *(const f16x8*)&Bh[cur][wc*NT*16 + nt*16 + lrow][loct*8];
        #pragma unroll
        for (int mt = 0; mt < MT; ++mt) {
            f16x8 ah = *(const f16x8*)&Ah[cur][wr*MT*16 + mt*16 + lrow][loct*8];
            #pragma unroll
            for (int nt = 0; nt < NT; ++nt)
                acc[mt][nt] = __builtin_amdgcn_mfma_f32_16x16x32_f16(ah, bh[nt], acc[mt][nt], 0, 0, 0);
        }
        if (more) {
            storeAB(cur ^ 1);
            __syncthreads();
            cur ^= 1;
        }
    }
    #pragma unroll
    for (int mt = 0; mt < MT; ++mt) {
        #pragma unroll
        for (int r4 = 0; r4 < 4; ++r4) {
            int m = m0 + wr*MT*16 + mt * 16 + loct * 4 + r4;
            long rowb = (long)b * M + m;
            #pragma unroll
            for (int nt = 0; nt < NT; ++nt) {
                int n = n0 + wc*NT*16 + nt * 16 + lrow;
                float v = acc[mt][nt][r4];
                if (EPI == HEPI_D34) {
                    if (n < DTR)           O0[rowb * DTR + n] = v;
                    else if (n < 2 * DTR)  Ob[rowb * 16 + (n - DTR)] = v;
                    else if (n < 48)       Oc[rowb * 16 + (n - 32)] = v;
                } else {
                    O0[rowb * N + n] = v;
                }
            }
        }
    }
}

// ---------------- weight prep: fp16 casts (round-3 version) ---------
#define SZ_WP  131072
#define SZ_WIN 262144
#define SZ_WO  131072
#define SZ_WC  24576
__global__ __launch_bounds__(256)
void pack_all(const float* __restrict__ Wp, const float* __restrict__ Win,
              const float* __restrict__ Wout, const float* __restrict__ Wx,
              __half* __restrict__ wph, __half* __restrict__ winh,
              __half* __restrict__ woh, __half* __restrict__ wch)
{
    int i = blockIdx.x * 256 + threadIdx.x;
    if (i < SZ_WP) { wph[i] = __float2half(Wp[i]); return; }
    i -= SZ_WP;
    if (i < SZ_WIN) { winh[i] = __float2half(Win[i]); return; }
    i -= SZ_WIN;
    if (i < SZ_WO) { woh[i] = __float2half(Wout[i]); return; }
    i -= SZ_WO;
    if (i < SZ_WC) wch[i] = __float2half(Wx[i]);   // (48, 512) row-major
}

// ---------------- depthwise causal conv (k=4) + silu ---------
__global__ __launch_bounds__(256)
void conv_silu_kernel(const __half* __restrict__ u_pre, const float* __restrict__ cw,
                      const float* __restrict__ cb, __half* __restrict__ u)
{
    long idx = (long)blockIdx.x * blockDim.x + threadIdx.x;
    int d = (int)(idx % DIN);
    long bl = idx / DIN;
    int l = (int)(bl % L);
    long brow = bl - l;
    float v = cb[d];
    #pragma unroll
    for (int j = 0; j < 4; ++j) {
        int li = l - 3 + j;
        if (li >= 0) v += __half2float(u_pre[(brow + li) * DIN + d]) * cw[d * 4 + j];
    }
    u[idx] = __float2half(silu_f(v));
}

// ---------------- chunked parallel selective scan, d-per-lane ----------------
#define NC 128
#define LC (L / NC)

__global__ __launch_bounds__(256)
void scan_phase1(const float* __restrict__ dtA, const __half* __restrict__ u,
                 const float* __restrict__ Bm, const float* __restrict__ A_log,
                 const float* __restrict__ Wdt, const float* __restrict__ bdt,
                 float* __restrict__ AX)
{
    __shared__ float sB[LC][DSTATE];
    __shared__ float sDt[LC][DTR];
    __shared__ __half sU[LC][256];
    const int gd = blockIdx.x & 1;
    const int c  = (blockIdx.x >> 1) & (NC - 1);
    const int b  = blockIdx.x >> 8;
    const int tid = threadIdx.x;
    const int d  = gd * 256 + tid;
    const int t0 = c * LC;
    float Arow[DSTATE];
    #pragma unroll
    for (int q = 0; q < 4; ++q) {
        float4 v = *(const float4*)&A_log[d * DSTATE + q * 4];
        Arow[q * 4 + 0] = -__expf(v.x) * LOG2E;
        Arow[q * 4 + 1] = -__expf(v.y) * LOG2E;
        Arow[q * 4 + 2] = -__expf(v.z) * LOG2E;
        Arow[q * 4 + 3] = -__expf(v.w) * LOG2E;
    }
    const float4 W0 = *(const float4*)&Wdt[d * DTR + 0];
    const float4 W1 = *(const float4*)&Wdt[d * DTR + 4];
    const float4 W2 = *(const float4*)&Wdt[d * DTR + 8];
    const float4 W3 = *(const float4*)&Wdt[d * DTR + 12];
    const float bd = bdt[d];
    {
        const __half* ub = u + ((long)b * L + t0) * DIN + gd * 256;
        #pragma unroll
        for (int j = 0; j < 4; ++j) {
            int i = tid + j * 256;
            int t = i >> 5, col = (i & 31) * 8;
            *(float4*)&sU[t][col] = *(const float4*)&ub[(long)t * DIN + col];
        }
        if (tid < 128) {
            const float* Bb = Bm  + ((long)b * L + t0) * DSTATE;
            const float* Db = dtA + ((long)b * L + t0) * DTR;
            *(float4*)&((float*)sB)[tid * 4]  = *(const float4*)&Bb[tid * 4];
            *(float4*)&((float*)sDt)[tid * 4] = *(const float4*)&Db[tid * 4];
        }
    }
    __syncthreads();
    float X[DSTATE];
    #pragma unroll
    for (int s = 0; s < DSTATE; ++s) X[s] = 0.f;
    float dsum = 0.f;   // P[s] = exp2(Arow[s]*sum_t dlt): deletes 16 VALU FMAs/step
    #pragma unroll 2
    for (int t = 0; t < LC; ++t) {
        float4 q0 = *(const float4*)&sDt[t][0];
        float4 q1 = *(const float4*)&sDt[t][4];
        float4 q2 = *(const float4*)&sDt[t][8];
        float4 q3 = *(const float4*)&sDt[t][12];
        float dp0 = fmaf(q0.x, W0.x, fmaf(q0.y, W0.y, fmaf(q0.z, W0.z, q0.w * W0.w)));
        float dp1 = fmaf(q1.x, W1.x, fmaf(q1.y, W1.y, fmaf(q1.z, W1.z, q1.w * W1.w)));
        float dp2 = fmaf(q2.x, W2.x, fmaf(q2.y, W2.y, fmaf(q2.z, W2.z, q2.w * W2.w)));
        float dp3 = fmaf(q3.x, W3.x, fmaf(q3.y, W3.y, fmaf(q3.z, W3.z, q3.w * W3.w)));
        float dlt = softplus_fast(((dp0 + dp1) + (dp2 + dp3)) + bd);
        dsum += dlt;
        float du  = dlt * __half2float(sU[t][tid]);
        float Brow[DSTATE];
        *(float4*)&Brow[0]  = *(const float4*)&sB[t][0];
        *(float4*)&Brow[4]  = *(const float4*)&sB[t][4];
        *(float4*)&Brow[8]  = *(const float4*)&sB[t][8];
        *(float4*)&Brow[12] = *(const float4*)&sB[t][12];
        #pragma unroll
        for (int s = 0; s < DSTATE; ++s) {
            float a = EXP2(dlt * Arow[s]);
            X[s] = fmaf(a, X[s], du * Brow[s]);
        }
    }
    float P[DSTATE];
    #pragma unroll
    for (int s = 0; s < DSTATE; ++s) P[s] = EXP2(dsum * Arow[s]);
    long o2 = ((((long)b * NC + c) * DIN + d) * DSTATE) * 2;
    #pragma unroll
    for (int q = 0; q < 8; ++q)
        *(float4*)&AX[o2 + q * 4] =
            make_float4(P[2*q], X[2*q], P[2*q+1], X[2*q+1]);
}

// cross-chunk scan: 32768 independent series; pure-ILP kernel.
__global__ __launch_bounds__(256)
void scan_phase2(const float* __restrict__ AX, float* __restrict__ Hout)
{
    int lane = blockIdx.x * 256 + threadIdx.x;   // 32768 total
    int b = lane >> 13;
    int rem = lane & 8191;
    const long cs = (long)DIN * DSTATE;
    const long base = (long)b * NC * cs + rem;
    float h = 0.f;
    float2 c0, c1, c2, c3, n0, n1, n2, n3;
    auto ld = [&](int c) -> float2 {
        return *(const float2*)&AX[2 * (base + (long)c * cs)];
    };
    c0 = ld(0); c1 = ld(1); c2 = ld(2); c3 = ld(3);
    n0 = ld(4); n1 = ld(5); n2 = ld(6); n3 = ld(7);
    for (int c = 0; c < NC; c += 4) {
        Hout[base + (long)(c+0) * cs] = h; h = fmaf(c0.x, h, c0.y);
        Hout[base + (long)(c+1) * cs] = h; h = fmaf(c1.x, h, c1.y);
        Hout[base + (long)(c+2) * cs] = h; h = fmaf(c2.x, h, c2.y);
        Hout[base + (long)(c+3) * cs] = h; h = fmaf(c3.x, h, c3.y);
        c0 = n0; c1 = n1; c2 = n2; c3 = n3;
        if (c + 8 < NC) { n0 = ld(c+8); n1 = ld(c+9); n2 = ld(c+10); n3 = ld(c+11); }
    }
}

__global__ __launch_bounds__(256)
void scan_phase3(const float* __restrict__ dtA, const __half* __restrict__ u,
                 const float* __restrict__ Bm, const float* __restrict__ Cm,
                 const __half* __restrict__ z, const float* __restrict__ A_log,
                 const float* __restrict__ Wdt, const float* __restrict__ bdt,
                 const float* __restrict__ Dp, const float* __restrict__ Hinit,
                 __half* __restrict__ y2h)
{
    __shared__ float sB[LC][DSTATE], sC[LC][DSTATE];
    __shared__ float sDt[LC][DTR];
    __shared__ __half sU[LC][256];
    __shared__ __half sZ[LC][256];
    const int gd = blockIdx.x & 1;
    const int c  = (blockIdx.x >> 1) & (NC - 1);
    const int b  = blockIdx.x >> 8;
    const int tid = threadIdx.x;
    const int d  = gd * 256 + tid;
    const int t0 = c * LC;
    float Arow[DSTATE];
    #pragma unroll
    for (int q = 0; q < 4; ++q) {
        float4 v = *(const float4*)&A_log[d * DSTATE + q * 4];
        Arow[q * 4 + 0] = -__expf(v.x) * LOG2E;
        Arow[q * 4 + 1] = -__expf(v.y) * LOG2E;
        Arow[q * 4 + 2] = -__expf(v.z) * LOG2E;
        Arow[q * 4 + 3] = -__expf(v.w) * LOG2E;
    }
    const float4 W0 = *(const float4*)&Wdt[d * DTR + 0];
    const float4 W1 = *(const float4*)&Wdt[d * DTR + 4];
    const float4 W2 = *(const float4*)&Wdt[d * DTR + 8];
    const float4 W3 = *(const float4*)&Wdt[d * DTR + 12];
    const float bd = bdt[d];
    {
        const __half* ub = u + ((long)b * L + t0) * DIN + gd * 256;
        const __half* zb = z + ((long)b * L + t0) * DIN + gd * 256;
        #pragma unroll
        for (int j = 0; j < 4; ++j) {
            int i = tid + j * 256;
            int t = i >> 5, col = (i & 31) * 8;
            *(float4*)&sU[t][col] = *(const float4*)&ub[(long)t * DIN + col];
            *(float4*)&sZ[t][col] = *(const float4*)&zb[(long)t * DIN + col];
        }
        if (tid < 128) {
            const float* Bb = Bm  + ((long)b * L + t0) * DSTATE;
            const float* Cb = Cm  + ((long)b * L + t0) * DSTATE;
            const float* Db = dtA + ((long)b * L + t0) * DTR;
            *(float4*)&((float*)sB)[tid * 4]  = *(const float4*)&Bb[tid * 4];
            *(float4*)&((float*)sC)[tid * 4]  = *(const float4*)&Cb[tid * 4];
            *(float4*)&((float*)sDt)[tid * 4] = *(const float4*)&Db[tid * 4];
        }
    }
    float h[DSTATE];
    {
        long o = (((long)b * NC + c) * DIN + d) * DSTATE;
        #pragma unroll
        for (int q = 0; q < 4; ++q) {
            float4 v = *(const float4*)&Hinit[o + q * 4];
            h[q * 4 + 0] = v.x; h[q * 4 + 1] = v.y;
            h[q * 4 + 2] = v.z; h[q * 4 + 3] = v.w;
        }
    }
    const float Dval = Dp[d];
    __syncthreads();
    #pragma unroll 2
    for (int t = 0; t < LC; ++t) {
        float4 q0 = *(const float4*)&sDt[t][0];
        float4 q1 = *(const float4*)&sDt[t][4];
        float4 q2 = *(const float4*)&sDt[t][8];
        float4 q3 = *(const float4*)&sDt[t][12];
        float dp0 = fmaf(q0.x, W0.x, fmaf(q0.y, W0.y, fmaf(q0.z, W0.z, q0.w * W0.w)));
        float dp1 = fmaf(q1.x, W1.x, fmaf(q1.y, W1.y, fmaf(q1.z, W1.z, q1.w * W1.w)));
        float dp2 = fmaf(q2.x, W2.x, fmaf(q2.y, W2.y, fmaf(q2.z, W2.z, q2.w * W2.w)));
        float dp3 = fmaf(q3.x, W3.x, fmaf(q3.y, W3.y, fmaf(q3.z, W3.z, q3.w * W3.w)));
        float dlt = softplus_fast(((dp0 + dp1) + (dp2 + dp3)) + bd);
        float uu = __half2float(sU[t][tid]);
        float zz = __half2float(sZ[t][tid]);
        float du = dlt * uu;
        float Brow[DSTATE], Crow[DSTATE];
        *(float4*)&Brow[0]  = *(const float4*)&sB[t][0];
        *(float4*)&Brow[4]  = *(const float4*)&sB[t][4];
        *(float4*)&Brow[8]  = *(const float4*)&sB[t][8];
        *(float4*)&Brow[12] = *(const float4*)&sB[t][12];
        *(float4*)&Crow[0]  = *(const float4*)&sC[t][0];
        *(float4*)&Crow[4]  = *(const float4*)&sC[t][4];
        *(float4*)&Crow[8]  = *(const float4*)&sC[t][8];
        *(float4*)&Crow[12] = *(const float4*)&sC[t][12];
        float y0 = 0.f, y1 = 0.f, y2 = 0.f, y3 = 0.f;
        #pragma unroll
        for (int s = 0; s < DSTATE; s += 4) {
            float a0 = EXP2(dlt * Arow[s+0]);
            float a1 = EXP2(dlt * Arow[s+1]);
            float a2 = EXP2(dlt * Arow[s+2]);
            float a3 = EXP2(dlt * Arow[s+3]);
            h[s+0] = fmaf(h[s+0], a0, du * Brow[s+0]);
            h[s+1] = fmaf(h[s+1], a1, du * Brow[s+1]);
            h[s+2] = fmaf(h[s+2], a2, du * Brow[s+2]);
            h[s+3] = fmaf(h[s+3], a3, du * Brow[s+3]);
            y0 = fmaf(h[s+0], Crow[s+0], y0);
            y1 = fmaf(h[s+1], Crow[s+1], y1);
            y2 = fmaf(h[s+2], Crow[s+2], y2);
            y3 = fmaf(h[s+3], Crow[s+3], y3);
        }
        float y = (y0 + y1) + (y2 + y3);
        long gidx = ((long)b * L + t0 + t) * DIN + d;
        y2h[gidx] = __float2half((y + uu * Dval) * silu_f(zz));
    }
}

// ---------------- LayerNorm over C + transpose to (B,C,L) ----------------
__global__ __launch_bounds__(256)
void ln_kernel(const float* __restrict__ X, const float* __restrict__ gamma,
               const float* __restrict__ beta, float* __restrict__ out)
{
    __shared__ float tile[32][257];
    __shared__ float sMu[32], sRs[32];
    const int l0 = blockIdx.x * 32;
    const int b  = blockIdx.y;
    const int tid = threadIdx.x;
    for (int i = tid; i < 32 * 256; i += 256) {
        int l = i >> 8, c = i & 255;
        tile[l][c] = X[((long)b * L + l0 + l) * CDIM + c];
    }
    __syncthreads();
    {
        int l = tid >> 3, sub = tid & 7;
        float s1 = 0.f, s2 = 0.f;
        for (int c = sub * 32; c < sub * 32 + 32; ++c) {
            float v = tile[l][c];
            s1 += v; s2 += v * v;
        }
        s1 += __shfl_xor(s1, 1); s2 += __shfl_xor(s2, 1);
        s1 += __shfl_xor(s1, 2); s2 += __shfl_xor(s2, 2);
        s1 += __shfl_xor(s1, 4); s2 += __shfl_xor(s2, 4);
        if (sub == 0) {
            float mu = s1 * (1.f / 256.f);
            float var = s2 * (1.f / 256.f) - mu * mu;
            sMu[l] = mu;
            sRs[l] = rsqrtf(var + 1e-5f);
        }
    }
    __syncthreads();
    for (int i = tid; i < 32 * 256; i += 256) {
        int ll = i & 31, c = i >> 5;
        float v = (tile[ll][c] - sMu[ll]) * sRs[ll] * gamma[c] + beta[c];
        out[((long)b * CDIM + c) * L + l0 + ll] = v;
    }
}

extern "C" void kernel_launch(void* const* d_in, const int* in_sizes, int n_in,
                              void* d_out, int out_size, void* d_ws, size_t ws_size,
                              hipStream_t stream)
{
    const float* sp   = (const float*)d_in[0];
    const float* fq   = (const float*)d_in[1];
    const float* Wp   = (const float*)d_in[2];
    const float* bp   = (const float*)d_in[3];
    const float* Win  = (const float*)d_in[4];
    const float* cw   = (const float*)d_in[5];
    const float* cb   = (const float*)d_in[6];
    const float* Wx   = (const float*)d_in[7];
    const float* Wdt  = (const float*)d_in[8];
    const float* bdt  = (const float*)d_in[9];
    const float* Alog = (const float*)d_in[10];
    const float* Dp   = (const float*)d_in[11];
    const float* Wout = (const float*)d_in[12];
    const float* gam  = (const float*)d_in[13];
    const float* bet  = (const float*)d_in[14];
    float* out = (float*)d_out;
    float* ws  = (float*)d_ws;

    const size_t NLD = (size_t)BATCH * L * DIN;   // 8.39M
    const size_t NLC = (size_t)BATCH * L * CDIM;  // 4.19M

    size_t off = 0;
    __half* u16   = (__half*)(ws + off); off += NLD / 2;  // pre-conv u
    __half* u16c  = (__half*)(ws + off); off += NLD / 2;  // post-conv silu(u)
    __half* z16   = (__half*)(ws + off); off += NLD / 2;
    __half* y16   = (__half*)(ws + off); off += NLD / 2;
    __half* xp16  = (__half*)(ws + off); off += NLC / 2;
    float*  xmix  = ws + off; off += NLC;
    float*  dtA   = ws + off; off += (size_t)BATCH * L * DTR;
    __half* wph   = (__half*)(ws + off); off += SZ_WP / 2;
    __half* winh  = (__half*)(ws + off); off += SZ_WIN / 2;
    __half* woh   = (__half*)(ws + off); off += SZ_WO / 2;
    __half* wch   = (__half*)(ws + off); off += SZ_WC / 2;
    float*  Bmb   = ws + off; off += (size_t)BATCH * L * DSTATE;
    float*  Cmb   = ws + off; off += (size_t)BATCH * L * DSTATE;
    float*  AX    = ws + off; off += (size_t)BATCH * NC * DIN * DSTATE * 2;
    float*  Hout  = ws + off; off += (size_t)BATCH * NC * DIN * DSTATE;

    dim3 blk(256);
    pack_all<<<dim3((SZ_WP + SZ_WIN + SZ_WO + SZ_WC) / 256), blk, 0, stream>>>(
        Wp, Win, Wout, Wx, wph, winh, woh, wch);

    // GEMM1: x_proj = x_cat @ Wp^T + bp  (A fp32 K-major; 128-tile, nBlk=2)
    hgemm128<HEPI_XP, true><<<dim3(BATCH * (L/128) * 2), blk, 0, stream>>>(
        sp, fq, nullptr, wph, bp, nullptr, xp16, nullptr,
        L, CDIM, 2 * CDIM, CDIM, (long)CDIM * L, 2);
    // GEMM2: xz = x_proj @ Win^T -> u16 / z16  (128-tile, nBlk=8)
    hgemm128<HEPI_UZ, false><<<dim3(BATCH * (L/128) * 8), blk, 0, stream>>>(
        nullptr, nullptr, xp16, winh, nullptr, nullptr, u16, z16,
        L, 2 * DIN, CDIM, 1 << 30, (long)L * CDIM, 8);

    conv_silu_kernel<<<dim3((int)(NLD / 256)), blk, 0, stream>>>(u16, cw, cb, u16c);
    // D34 rank-16: dbc = u @ Wx^T (N=48: dt|Bm|Cm). delta folded into scans.
    hgemm<HEPI_D34, false, 2><<<dim3(BATCH * (L/64) * 1), blk, 0, stream>>>(
        nullptr, nullptr, u16c, wch, nullptr, dtA, nullptr, nullptr, Bmb, Cmb,
        L, 48, DIN, 1 << 30, (long)L * DIN, 1);

    scan_phase1<<<dim3(BATCH * NC * 2), blk, 0, stream>>>(
        dtA, u16c, Bmb, Alog, Wdt, bdt, AX);
    scan_phase2<<<dim3(BATCH * DIN * DSTATE / 256), blk, 0, stream>>>(AX, Hout);
    scan_phase3<<<dim3(BATCH * NC * 2), blk, 0, stream>>>(
        dtA, u16c, Bmb, Cmb, z16, Alog, Wdt, bdt, Dp, Hout, y16);

    // GEMM5: x_mixed = y2 @ Wout^T  (128-tile, nBlk=2)
    hgemm128<HEPI_F32, false><<<dim3(BATCH * (L/128) * 2), blk, 0, stream>>>(
        nullptr, nullptr, y16, woh, nullptr, xmix, nullptr, nullptr,
        L, CDIM, DIN, 1 << 30, (long)L * DIN, 2);
    ln_kernel<<<dim3(L / 32, BATCH), blk, 0, stream>>>(xmix, gam, bet, out);
}

// Round 6
// 320.070 us; speedup vs baseline: 1.1236x; 1.1178x over previous
//
#include <hip/hip_runtime.h>
#include <hip/hip_fp16.h>
#include <math.h>

#define L 4096
#define CDIM 256
#define DIN 512
#define DSTATE 16
#define DTR 16
#define BATCH 4

using f32x4  = __attribute__((ext_vector_type(4))) float;
using f32x2  = __attribute__((ext_vector_type(2))) float;
using f16x8  = __attribute__((ext_vector_type(8))) _Float16;

#define LOG2E 1.44269504088896f

#if __has_builtin(__builtin_amdgcn_exp2f)
#define EXP2(x) __builtin_amdgcn_exp2f(x)
#else
#define EXP2(x) __expf((x) * 0.69314718056f)
#endif

__device__ __forceinline__ float silu_f(float x) {
    return __fdividef(x, 1.f + __expf(-x));
}
__device__ __forceinline__ float softplus_fast(float x) {
    return (x > 20.f) ? x : __logf(1.f + __expf(x));
}
__device__ __forceinline__ unsigned pk2h(float a, float b) {
    __half2 h = __floats2half2_rn(a, b);
    return *reinterpret_cast<unsigned*>(&h);
}

#define LDK 40

// LESSONS (measured, do not repeat):
//  - r1: lgkm-only barrier + depth-2 reg prefetch regressed (6.6->4.4 MfmaUtil).
//  - r4: GEMM1+GEMM2 fusion neutral (stall-bound; blocks x k-iters unchanged).
//  - r4: replacing 16 exp2 (trans pipe, hidden under VALU) with 15 serial VALU
//    muls REGRESSED scans ~+23us. Delete VALU ops, keep trans ops.
//  - r5: 128x128 tile regressed GEMMs (74 vs ~52us): 40KB LDS -> 4 blocks/CU and
//    small grids -> occupancy 29->21%. These GEMMs are stall-bound; resident-block
//    count hides stalls. 64-tile/LDK40/5-blocks-per-CU is the measured optimum.
//  - WRITE_SIZE on early dispatches includes harness memset traffic (artifact).

enum { HEPI_XP = 0, HEPI_UZ = 1, HEPI_F32 = 2, HEPI_D34 = 3 };

// ====== fp16 MFMA GEMM: 64-row tiles, double-buffered single-barrier (r3 exact) ===
template<int EPI, bool A_F32KM, int NT>
__global__ __launch_bounds__(256)
void hgemm(const float* __restrict__ Af0, const float* __restrict__ Af1,
           const __half* __restrict__ Ah_g, const __half* __restrict__ Bh_g,
           const float* __restrict__ bias,
           float* __restrict__ O0, __half* __restrict__ Oh0, __half* __restrict__ Oh1,
           float* __restrict__ Ob, float* __restrict__ Oc,
           int M, int N, int K, int kSplit, long strideAb, int nBlk)
{
    constexpr int BM = 64, MT = 2;
    constexpr int BN = 2 * NT * 16;
    constexpr int BSEG = BN / 64;
    __shared__ __align__(16) _Float16 Ah[2][BM][LDK];
    __shared__ __align__(16) _Float16 Bh[2][BN][LDK];
    const int mBlk = M / BM;
    const int bid = blockIdx.x;
    const int r = bid & 7, q = bid >> 3;
    const int ni = q % nBlk;
    const int mg = (q / nBlk) * 8 + r;
    const int b = mg / mBlk, m_idx = mg - b * mBlk;
    const int n0 = ni * BN, m0 = m_idx * BM;
    const int tid  = threadIdx.x;
    const int lane = tid & 63;
    const int w    = tid >> 6;
    const int wr   = w >> 1, wc = w & 1;
    const int lrow = lane & 15;
    const int loct = lane >> 4;

    f32x4 acc[MT][NT];
    #pragma unroll
    for (int i = 0; i < MT; ++i)
        #pragma unroll
        for (int j = 0; j < NT; ++j)
            acc[i][j] = (f32x4){0.f, 0.f, 0.f, 0.f};

    const int sOct = tid & 3, sRow = tid >> 2;
    float va[8];
    uint4 pa, pb[BSEG];

    auto loadA = [&](int kk) {
        if (A_F32KM) {
            int m = tid & 63, ks = tid >> 6;
            #pragma unroll
            for (int j = 0; j < 8; ++j) {
                int kg = kk + ks * 8 + j;
                const float* Ap; int kl;
                if (kg < kSplit) { Ap = Af0; kl = kg; } else { Ap = Af1; kl = kg - kSplit; }
                va[j] = Ap[(long)b * strideAb + (long)kl * M + m0 + m];
            }
        } else {
            pa = *(const uint4*)(Ah_g + (long)b * strideAb +
                                 (long)(m0 + sRow) * K + kk + sOct * 8);
        }
    };
    auto loadB = [&](int kk) {
        #pragma unroll
        for (int p = 0; p < BSEG; ++p) {
            int ng = n0 + sRow + p * 64;
            if (EPI == HEPI_D34 && ng >= N)
                pb[p] = make_uint4(0, 0, 0, 0);
            else
                pb[p] = *(const uint4*)(Bh_g + (long)ng * K + kk + sOct * 8);
        }
    };
    auto storeAB = [&](int buf) {
        if (A_F32KM) {
            int m = tid & 63, ks = tid >> 6;
            uint4 h;
            h.x = pk2h(va[0], va[1]);
            h.y = pk2h(va[2], va[3]);
            h.z = pk2h(va[4], va[5]);
            h.w = pk2h(va[6], va[7]);
            *(uint4*)&Ah[buf][m][ks * 8] = h;
        } else {
            *(uint4*)&Ah[buf][sRow][sOct * 8] = pa;
        }
        #pragma unroll
        for (int p = 0; p < BSEG; ++p)
            *(uint4*)&Bh[buf][sRow + p * 64][sOct * 8] = pb[p];
    };

    loadA(0); loadB(0);
    storeAB(0);
    __syncthreads();
    int cur = 0;
    for (int kk = 0; kk < K; kk += 32) {
        const bool more = (kk + 32 < K);
        if (more) { loadA(kk + 32); loadB(kk + 32); }
        f16x8 bh[NT];
        #pragma unroll
        for (int nt = 0; nt < NT; ++nt)
            bh[nt] = *(const f16x8*)&Bh[cur][wc*NT*16 + nt*16 + lrow][loct*8];
        #pragma unroll
        for (int mt = 0; mt < MT; ++mt) {
            f16x8 ah = *(const f16x8*)&Ah[cur][wr*MT*16 + mt*16 + lrow][loct*8];
            #pragma unroll
            for (int nt = 0; nt < NT; ++nt)
                acc[mt][nt] = __builtin_amdgcn_mfma_f32_16x16x32_f16(ah, bh[nt], acc[mt][nt], 0, 0, 0);
        }
        if (more) {
            storeAB(cur ^ 1);
            __syncthreads();
            cur ^= 1;
        }
    }
    #pragma unroll
    for (int mt = 0; mt < MT; ++mt) {
        #pragma unroll
        for (int r4 = 0; r4 < 4; ++r4) {
            int m = m0 + wr*MT*16 + mt * 16 + loct * 4 + r4;
            long rowb = (long)b * M + m;
            #pragma unroll
            for (int nt = 0; nt < NT; ++nt) {
                int n = n0 + wc*NT*16 + nt * 16 + lrow;
                float v = acc[mt][nt][r4];
                if (EPI == HEPI_XP) {
                    Oh0[rowb * N + n] = __float2half(v + bias[n]);
                } else if (EPI == HEPI_UZ) {
                    if (n < DIN) Oh0[rowb * DIN + n] = __float2half(v);
                    else         Oh1[rowb * DIN + (n - DIN)] = __float2half(v);
                } else if (EPI == HEPI_D34) {
                    if (n < DTR)           O0[rowb * DTR + n] = v;
                    else if (n < 2 * DTR)  Ob[rowb * 16 + (n - DTR)] = v;
                    else if (n < 48)       Oc[rowb * 16 + (n - 32)] = v;
                } else {
                    O0[rowb * N + n] = v;
                }
            }
        }
    }
}

// ---------------- weight prep: fp16 casts ---------
#define SZ_WP  131072
#define SZ_WIN 262144
#define SZ_WO  131072
#define SZ_WC  24576
__global__ __launch_bounds__(256)
void pack_all(const float* __restrict__ Wp, const float* __restrict__ Win,
              const float* __restrict__ Wout, const float* __restrict__ Wx,
              __half* __restrict__ wph, __half* __restrict__ winh,
              __half* __restrict__ woh, __half* __restrict__ wch)
{
    int i = blockIdx.x * 256 + threadIdx.x;
    if (i < SZ_WP) { wph[i] = __float2half(Wp[i]); return; }
    i -= SZ_WP;
    if (i < SZ_WIN) { winh[i] = __float2half(Win[i]); return; }
    i -= SZ_WIN;
    if (i < SZ_WO) { woh[i] = __float2half(Wout[i]); return; }
    i -= SZ_WO;
    if (i < SZ_WC) wch[i] = __float2half(Wx[i]);   // (48, 512) row-major
}

// ---------------- depthwise causal conv (k=4) + silu ---------
__global__ __launch_bounds__(256)
void conv_silu_kernel(const __half* __restrict__ u_pre, const float* __restrict__ cw,
                      const float* __restrict__ cb, __half* __restrict__ u)
{
    long idx = (long)blockIdx.x * blockDim.x + threadIdx.x;
    int d = (int)(idx % DIN);
    long bl = idx / DIN;
    int l = (int)(bl % L);
    long brow = bl - l;
    float v = cb[d];
    #pragma unroll
    for (int j = 0; j < 4; ++j) {
        int li = l - 3 + j;
        if (li >= 0) v += __half2float(u_pre[(brow + li) * DIN + d]) * cw[d * 4 + j];
    }
    u[idx] = __float2half(silu_f(v));
}

// ---------------- chunked parallel selective scan, d-per-lane ----------------
// VALU-issue-bound (65% busy, 0 conflicts). This round: packed-f32 math.
// CDNA v_pk_fma_f32/v_pk_mul_f32 do 2 f32 ops per issue slot; the f32x2
// ext-vector + __builtin_elementwise_fma formulation lets clang emit them
// (falls back to scalar if unavailable -> correctness/perf-neutral).
// Exps stay on the trans pipe (r4 lesson).
#define NC 128
#define LC (L / NC)

__device__ __forceinline__ f32x2 fma2(f32x2 a, f32x2 b, f32x2 c) {
    return __builtin_elementwise_fma(a, b, c);
}

__global__ __launch_bounds__(256)
void scan_phase1(const float* __restrict__ dtA, const __half* __restrict__ u,
                 const float* __restrict__ Bm, const float* __restrict__ A_log,
                 const float* __restrict__ Wdt, const float* __restrict__ bdt,
                 float* __restrict__ AX)
{
    __shared__ float sB[LC][DSTATE];
    __shared__ float sDt[LC][DTR];
    __shared__ __half sU[LC][256];
    const int gd = blockIdx.x & 1;
    const int c  = (blockIdx.x >> 1) & (NC - 1);
    const int b  = blockIdx.x >> 8;
    const int tid = threadIdx.x;
    const int d  = gd * 256 + tid;
    const int t0 = c * LC;
    f32x2 A2[8];
    #pragma unroll
    for (int q = 0; q < 4; ++q) {
        float4 v = *(const float4*)&A_log[d * DSTATE + q * 4];
        A2[2*q]   = (f32x2){-__expf(v.x) * LOG2E, -__expf(v.y) * LOG2E};
        A2[2*q+1] = (f32x2){-__expf(v.z) * LOG2E, -__expf(v.w) * LOG2E};
    }
    f32x2 Wv[8];
    #pragma unroll
    for (int q = 0; q < 4; ++q) {
        float4 v = *(const float4*)&Wdt[d * DTR + q * 4];
        Wv[2*q]   = (f32x2){v.x, v.y};
        Wv[2*q+1] = (f32x2){v.z, v.w};
    }
    const float bd = bdt[d];
    {
        const __half* ub = u + ((long)b * L + t0) * DIN + gd * 256;
        #pragma unroll
        for (int j = 0; j < 4; ++j) {
            int i = tid + j * 256;
            int t = i >> 5, col = (i & 31) * 8;
            *(float4*)&sU[t][col] = *(const float4*)&ub[(long)t * DIN + col];
        }
        if (tid < 128) {
            const float* Bb = Bm  + ((long)b * L + t0) * DSTATE;
            const float* Db = dtA + ((long)b * L + t0) * DTR;
            *(float4*)&((float*)sB)[tid * 4]  = *(const float4*)&Bb[tid * 4];
            *(float4*)&((float*)sDt)[tid * 4] = *(const float4*)&Db[tid * 4];
        }
    }
    __syncthreads();
    f32x2 X2[8];
    #pragma unroll
    for (int k = 0; k < 8; ++k) X2[k] = (f32x2){0.f, 0.f};
    float dsum = 0.f;   // P[s] = exp2(Arow[s]*sum_t dlt): 16 FMAs/step -> 1 add
    #pragma unroll 2
    for (int t = 0; t < LC; ++t) {
        float qd[16], br[16];
        *(float4*)&qd[0]  = *(const float4*)&sDt[t][0];
        *(float4*)&qd[4]  = *(const float4*)&sDt[t][4];
        *(float4*)&qd[8]  = *(const float4*)&sDt[t][8];
        *(float4*)&qd[12] = *(const float4*)&sDt[t][12];
        f32x2 dpA = (f32x2){0.f, 0.f}, dpB = (f32x2){0.f, 0.f};
        #pragma unroll
        for (int k = 0; k < 8; k += 2) {
            dpA = fma2(*(const f32x2*)&qd[2*k],     Wv[k],     dpA);
            dpB = fma2(*(const f32x2*)&qd[2*k+2],   Wv[k+1],   dpB);
        }
        float dlt = softplus_fast(((dpA.x + dpA.y) + (dpB.x + dpB.y)) + bd);
        dsum += dlt;
        float du = dlt * __half2float(sU[t][tid]);
        f32x2 du2  = (f32x2){du, du};
        f32x2 dlt2 = (f32x2){dlt, dlt};
        *(float4*)&br[0]  = *(const float4*)&sB[t][0];
        *(float4*)&br[4]  = *(const float4*)&sB[t][4];
        *(float4*)&br[8]  = *(const float4*)&sB[t][8];
        *(float4*)&br[12] = *(const float4*)&sB[t][12];
        #pragma unroll
        for (int k = 0; k < 8; ++k) {
            f32x2 tt = dlt2 * A2[k];
            f32x2 a2;
            a2.x = EXP2(tt.x);
            a2.y = EXP2(tt.y);
            X2[k] = fma2(a2, X2[k], du2 * *(const f32x2*)&br[2*k]);
        }
    }
    f32x2 ds2 = (f32x2){dsum, dsum};
    long o2 = ((((long)b * NC + c) * DIN + d) * DSTATE) * 2;
    #pragma unroll
    for (int k = 0; k < 8; ++k) {
        f32x2 pt = ds2 * A2[k];
        float p0 = EXP2(pt.x), p1 = EXP2(pt.y);
        *(float4*)&AX[o2 + k * 4] = make_float4(p0, X2[k].x, p1, X2[k].y);
    }
}

// cross-chunk scan: 32768 independent series; pure-ILP kernel.
__global__ __launch_bounds__(256)
void scan_phase2(const float* __restrict__ AX, float* __restrict__ Hout)
{
    int lane = blockIdx.x * 256 + threadIdx.x;   // 32768 total
    int b = lane >> 13;
    int rem = lane & 8191;
    const long cs = (long)DIN * DSTATE;
    const long base = (long)b * NC * cs + rem;
    float h = 0.f;
    float2 c0, c1, c2, c3, n0, n1, n2, n3;
    auto ld = [&](int c) -> float2 {
        return *(const float2*)&AX[2 * (base + (long)c * cs)];
    };
    c0 = ld(0); c1 = ld(1); c2 = ld(2); c3 = ld(3);
    n0 = ld(4); n1 = ld(5); n2 = ld(6); n3 = ld(7);
    for (int c = 0; c < NC; c += 4) {
        Hout[base + (long)(c+0) * cs] = h; h = fmaf(c0.x, h, c0.y);
        Hout[base + (long)(c+1) * cs] = h; h = fmaf(c1.x, h, c1.y);
        Hout[base + (long)(c+2) * cs] = h; h = fmaf(c2.x, h, c2.y);
        Hout[base + (long)(c+3) * cs] = h; h = fmaf(c3.x, h, c3.y);
        c0 = n0; c1 = n1; c2 = n2; c3 = n3;
        if (c + 8 < NC) { n0 = ld(c+8); n1 = ld(c+9); n2 = ld(c+10); n3 = ld(c+11); }
    }
}

__global__ __launch_bounds__(256)
void scan_phase3(const float* __restrict__ dtA, const __half* __restrict__ u,
                 const float* __restrict__ Bm, const float* __restrict__ Cm,
                 const __half* __restrict__ z, const float* __restrict__ A_log,
                 const float* __restrict__ Wdt, const float* __restrict__ bdt,
                 const float* __restrict__ Dp, const float* __restrict__ Hinit,
                 __half* __restrict__ y2h)
{
    __shared__ float sB[LC][DSTATE], sC[LC][DSTATE];
    __shared__ float sDt[LC][DTR];
    __shared__ __half sU[LC][256];
    __shared__ __half sZ[LC][256];
    const int gd = blockIdx.x & 1;
    const int c  = (blockIdx.x >> 1) & (NC - 1);
    const int b  = blockIdx.x >> 8;
    const int tid = threadIdx.x;
    const int d  = gd * 256 + tid;
    const int t0 = c * LC;
    f32x2 A2[8];
    #pragma unroll
    for (int q = 0; q < 4; ++q) {
        float4 v = *(const float4*)&A_log[d * DSTATE + q * 4];
        A2[2*q]   = (f32x2){-__expf(v.x) * LOG2E, -__expf(v.y) * LOG2E};
        A2[2*q+1] = (f32x2){-__expf(v.z) * LOG2E, -__expf(v.w) * LOG2E};
    }
    f32x2 Wv[8];
    #pragma unroll
    for (int q = 0; q < 4; ++q) {
        float4 v = *(const float4*)&Wdt[d * DTR + q * 4];
        Wv[2*q]   = (f32x2){v.x, v.y};
        Wv[2*q+1] = (f32x2){v.z, v.w};
    }
    const float bd = bdt[d];
    {
        const __half* ub = u + ((long)b * L + t0) * DIN + gd * 256;
        const __half* zb = z + ((long)b * L + t0) * DIN + gd * 256;
        #pragma unroll
        for (int j = 0; j < 4; ++j) {
            int i = tid + j * 256;
            int t = i >> 5, col = (i & 31) * 8;
            *(float4*)&sU[t][col] = *(const float4*)&ub[(long)t * DIN + col];
            *(float4*)&sZ[t][col] = *(const float4*)&zb[(long)t * DIN + col];
        }
        if (tid < 128) {
            const float* Bb = Bm  + ((long)b * L + t0) * DSTATE;
            const float* Cb = Cm  + ((long)b * L + t0) * DSTATE;
            const float* Db = dtA + ((long)b * L + t0) * DTR;
            *(float4*)&((float*)sB)[tid * 4]  = *(const float4*)&Bb[tid * 4];
            *(float4*)&((float*)sC)[tid * 4]  = *(const float4*)&Cb[tid * 4];
            *(float4*)&((float*)sDt)[tid * 4] = *(const float4*)&Db[tid * 4];
        }
    }
    f32x2 h2[8];
    {
        long o = (((long)b * NC + c) * DIN + d) * DSTATE;
        #pragma unroll
        for (int q = 0; q < 4; ++q) {
            float4 v = *(const float4*)&Hinit[o + q * 4];
            h2[2*q]   = (f32x2){v.x, v.y};
            h2[2*q+1] = (f32x2){v.z, v.w};
        }
    }
    const float Dval = Dp[d];
    const long gbase = ((long)b * L + t0) * DIN + d;
    __syncthreads();
    #pragma unroll 2
    for (int t = 0; t < LC; ++t) {
        float qd[16], br[16], cr[16];
        *(float4*)&qd[0]  = *(const float4*)&sDt[t][0];
        *(float4*)&qd[4]  = *(const float4*)&sDt[t][4];
        *(float4*)&qd[8]  = *(const float4*)&sDt[t][8];
        *(float4*)&qd[12] = *(const float4*)&sDt[t][12];
        f32x2 dpA = (f32x2){0.f, 0.f}, dpB = (f32x2){0.f, 0.f};
        #pragma unroll
        for (int k = 0; k < 8; k += 2) {
            dpA = fma2(*(const f32x2*)&qd[2*k],   Wv[k],   dpA);
            dpB = fma2(*(const f32x2*)&qd[2*k+2], Wv[k+1], dpB);
        }
        float dlt = softplus_fast(((dpA.x + dpA.y) + (dpB.x + dpB.y)) + bd);
        float uu = __half2float(sU[t][tid]);
        float zz = __half2float(sZ[t][tid]);
        float du = dlt * uu;
        f32x2 du2  = (f32x2){du, du};
        f32x2 dlt2 = (f32x2){dlt, dlt};
        *(float4*)&br[0]  = *(const float4*)&sB[t][0];
        *(float4*)&br[4]  = *(const float4*)&sB[t][4];
        *(float4*)&br[8]  = *(const float4*)&sB[t][8];
        *(float4*)&br[12] = *(const float4*)&sB[t][12];
        *(float4*)&cr[0]  = *(const float4*)&sC[t][0];
        *(float4*)&cr[4]  = *(const float4*)&sC[t][4];
        *(float4*)&cr[8]  = *(const float4*)&sC[t][8];
        *(float4*)&cr[12] = *(const float4*)&sC[t][12];
        f32x2 y2a = (f32x2){0.f, 0.f}, y2b = (f32x2){0.f, 0.f};
        f32x2 y2c = (f32x2){0.f, 0.f}, y2d = (f32x2){0.f, 0.f};
        #pragma unroll
        for (int k = 0; k < 8; k += 4) {
            f32x2 t0v = dlt2 * A2[k+0];
            f32x2 t1v = dlt2 * A2[k+1];
            f32x2 t2v = dlt2 * A2[k+2];
            f32x2 t3v = dlt2 * A2[k+3];
            f32x2 a0, a1, a2v, a3;
            a0.x = EXP2(t0v.x); a0.y = EXP2(t0v.y);
            a1.x = EXP2(t1v.x); a1.y = EXP2(t1v.y);
            a2v.x = EXP2(t2v.x); a2v.y = EXP2(t2v.y);
            a3.x = EXP2(t3v.x); a3.y = EXP2(t3v.y);
            h2[k+0] = fma2(h2[k+0], a0,  du2 * *(const f32x2*)&br[2*k+0]);
            h2[k+1] = fma2(h2[k+1], a1,  du2 * *(const f32x2*)&br[2*k+2]);
            h2[k+2] = fma2(h2[k+2], a2v, du2 * *(const f32x2*)&br[2*k+4]);
            h2[k+3] = fma2(h2[k+3], a3,  du2 * *(const f32x2*)&br[2*k+6]);
            y2a = fma2(h2[k+0], *(const f32x2*)&cr[2*k+0], y2a);
            y2b = fma2(h2[k+1], *(const f32x2*)&cr[2*k+2], y2b);
            y2c = fma2(h2[k+2], *(const f32x2*)&cr[2*k+4], y2c);
            y2d = fma2(h2[k+3], *(const f32x2*)&cr[2*k+6], y2d);
        }
        f32x2 ys = (y2a + y2b) + (y2c + y2d);
        float y = ys.x + ys.y;
        y2h[gbase + t * DIN] = __float2half((y + uu * Dval) * silu_f(zz));
    }
}

// ---------------- LayerNorm over C + transpose to (B,C,L) ----------------
__global__ __launch_bounds__(256)
void ln_kernel(const float* __restrict__ X, const float* __restrict__ gamma,
               const float* __restrict__ beta, float* __restrict__ out)
{
    __shared__ float tile[32][257];
    __shared__ float sMu[32], sRs[32];
    const int l0 = blockIdx.x * 32;
    const int b  = blockIdx.y;
    const int tid = threadIdx.x;
    for (int i = tid; i < 32 * 256; i += 256) {
        int l = i >> 8, c = i & 255;
        tile[l][c] = X[((long)b * L + l0 + l) * CDIM + c];
    }
    __syncthreads();
    {
        int l = tid >> 3, sub = tid & 7;
        float s1 = 0.f, s2 = 0.f;
        for (int c = sub * 32; c < sub * 32 + 32; ++c) {
            float v = tile[l][c];
            s1 += v; s2 += v * v;
        }
        s1 += __shfl_xor(s1, 1); s2 += __shfl_xor(s2, 1);
        s1 += __shfl_xor(s1, 2); s2 += __shfl_xor(s2, 2);
        s1 += __shfl_xor(s1, 4); s2 += __shfl_xor(s2, 4);
        if (sub == 0) {
            float mu = s1 * (1.f / 256.f);
            float var = s2 * (1.f / 256.f) - mu * mu;
            sMu[l] = mu;
            sRs[l] = rsqrtf(var + 1e-5f);
        }
    }
    __syncthreads();
    for (int i = tid; i < 32 * 256; i += 256) {
        int ll = i & 31, c = i >> 5;
        float v = (tile[ll][c] - sMu[ll]) * sRs[ll] * gamma[c] + beta[c];
        out[((long)b * CDIM + c) * L + l0 + ll] = v;
    }
}

extern "C" void kernel_launch(void* const* d_in, const int* in_sizes, int n_in,
                              void* d_out, int out_size, void* d_ws, size_t ws_size,
                              hipStream_t stream)
{
    const float* sp   = (const float*)d_in[0];
    const float* fq   = (const float*)d_in[1];
    const float* Wp   = (const float*)d_in[2];
    const float* bp   = (const float*)d_in[3];
    const float* Win  = (const float*)d_in[4];
    const float* cw   = (const float*)d_in[5];
    const float* cb   = (const float*)d_in[6];
    const float* Wx   = (const float*)d_in[7];
    const float* Wdt  = (const float*)d_in[8];
    const float* bdt  = (const float*)d_in[9];
    const float* Alog = (const float*)d_in[10];
    const float* Dp   = (const float*)d_in[11];
    const float* Wout = (const float*)d_in[12];
    const float* gam  = (const float*)d_in[13];
    const float* bet  = (const float*)d_in[14];
    float* out = (float*)d_out;
    float* ws  = (float*)d_ws;

    const size_t NLD = (size_t)BATCH * L * DIN;   // 8.39M
    const size_t NLC = (size_t)BATCH * L * CDIM;  // 4.19M

    size_t off = 0;
    __half* u16   = (__half*)(ws + off); off += NLD / 2;  // pre-conv u
    __half* u16c  = (__half*)(ws + off); off += NLD / 2;  // post-conv silu(u)
    __half* z16   = (__half*)(ws + off); off += NLD / 2;
    __half* y16   = (__half*)(ws + off); off += NLD / 2;
    __half* xp16  = (__half*)(ws + off); off += NLC / 2;
    float*  xmix  = ws + off; off += NLC;
    float*  dtA   = ws + off; off += (size_t)BATCH * L * DTR;
    __half* wph   = (__half*)(ws + off); off += SZ_WP / 2;
    __half* winh  = (__half*)(ws + off); off += SZ_WIN / 2;
    __half* woh   = (__half*)(ws + off); off += SZ_WO / 2;
    __half* wch   = (__half*)(ws + off); off += SZ_WC / 2;
    float*  Bmb   = ws + off; off += (size_t)BATCH * L * DSTATE;
    float*  Cmb   = ws + off; off += (size_t)BATCH * L * DSTATE;
    float*  AX    = ws + off; off += (size_t)BATCH * NC * DIN * DSTATE * 2;
    float*  Hout  = ws + off; off += (size_t)BATCH * NC * DIN * DSTATE;

    dim3 blk(256);
    pack_all<<<dim3((SZ_WP + SZ_WIN + SZ_WO + SZ_WC) / 256), blk, 0, stream>>>(
        Wp, Win, Wout, Wx, wph, winh, woh, wch);

    // GEMM1: x_proj = x_cat @ Wp^T + bp  (A fp32 K-major; 64-tile, nBlk=4)
    hgemm<HEPI_XP, true, 2><<<dim3(BATCH * (L/64) * 4), blk, 0, stream>>>(
        sp, fq, nullptr, wph, bp, nullptr, xp16, nullptr, nullptr, nullptr,
        L, CDIM, 2 * CDIM, CDIM, (long)CDIM * L, 4);
    // GEMM2: xz = x_proj @ Win^T -> u16 / z16  (64-tile, nBlk=8)
    hgemm<HEPI_UZ, false, 4><<<dim3(BATCH * (L/64) * 8), blk, 0, stream>>>(
        nullptr, nullptr, xp16, winh, nullptr, nullptr, u16, z16, nullptr, nullptr,
        L, 2 * DIN, CDIM, 1 << 30, (long)L * CDIM, 8);

    conv_silu_kernel<<<dim3((int)(NLD / 256)), blk, 0, stream>>>(u16, cw, cb, u16c);
    // D34 rank-16: dbc = u @ Wx^T (N=48: dt|Bm|Cm). delta folded into scans.
    hgemm<HEPI_D34, false, 2><<<dim3(BATCH * (L/64) * 1), blk, 0, stream>>>(
        nullptr, nullptr, u16c, wch, nullptr, dtA, nullptr, nullptr, Bmb, Cmb,
        L, 48, DIN, 1 << 30, (long)L * DIN, 1);

    scan_phase1<<<dim3(BATCH * NC * 2), blk, 0, stream>>>(
        dtA, u16c, Bmb, Alog, Wdt, bdt, AX);
    scan_phase2<<<dim3(BATCH * DIN * DSTATE / 256), blk, 0, stream>>>(AX, Hout);
    scan_phase3<<<dim3(BATCH * NC * 2), blk, 0, stream>>>(
        dtA, u16c, Bmb, Cmb, z16, Alog, Wdt, bdt, Dp, Hout, y16);

    // GEMM5: x_mixed = y2 @ Wout^T  (64-tile, nBlk=4)
    hgemm<HEPI_F32, false, 2><<<dim3(BATCH * (L/64) * 4), blk, 0, stream>>>(
        nullptr, nullptr, y16, woh, nullptr, xmix, nullptr, nullptr, nullptr, nullptr,
        L, CDIM, DIN, 1 << 30, (long)L * DIN, 4);
    ln_kernel<<<dim3(L / 32, BATCH), blk, 0, stream>>>(xmix, gam, bet, out);
}

// Round 8
// 300.558 us; speedup vs baseline: 1.1965x; 1.0649x over previous
//
#include <hip/hip_runtime.h>
#include <hip/hip_fp16.h>
#include <math.h>

#define L 4096
#define CDIM 256
#define DIN 512
#define DSTATE 16
#define DTR 16
#define BATCH 4

using f32x4  = __attribute__((ext_vector_type(4))) float;
using f32x2  = __attribute__((ext_vector_type(2))) float;
using f16x8  = __attribute__((ext_vector_type(8))) _Float16;

#define LOG2E 1.44269504088896f

#if __has_builtin(__builtin_amdgcn_exp2f)
#define EXP2(x) __builtin_amdgcn_exp2f(x)
#else
#define EXP2(x) __expf((x) * 0.69314718056f)
#endif

__device__ __forceinline__ float silu_f(float x) {
    return __fdividef(x, 1.f + __expf(-x));
}
__device__ __forceinline__ float softplus_fast(float x) {
    return (x > 20.f) ? x : __logf(1.f + __expf(x));
}
__device__ __forceinline__ unsigned pk2h(float a, float b) {
    __half2 h = __floats2half2_rn(a, b);
    return *reinterpret_cast<unsigned*>(&h);
}

// async global->LDS, 16B per lane, dest = wave-uniform base + lane*16
__device__ __forceinline__ void gload_lds16(const void* g, void* l) {
    __builtin_amdgcn_global_load_lds(
        (const __attribute__((address_space(1))) void*)g,
        (__attribute__((address_space(3))) void*)l, 16, 0, 0);
}

// LESSONS (measured, do not repeat):
//  - r1: lgkm-only barrier + depth-2 reg prefetch regressed (6.6->4.4 MfmaUtil).
//  - r4: GEMM1+GEMM2 fusion neutral (stall-bound; blocks x k-iters unchanged).
//  - r4: replacing 16 exp2 (trans pipe, hidden under VALU) with 15 serial VALU
//    muls REGRESSED scans ~+23us. Delete VALU ops, keep trans ops.
//  - r5: 128x128 tile regressed GEMMs: occupancy hides stalls here; 64-tile wins.
//  - r6: pk-f32 (f32x2) scan math WORKED: scans left the top-5. 320.1us.
//  - r7: bench infra failure (container died in setup); gload_lds design audited
//    clean (alignment, bounds, uniform barriers, swizzle involution) -> resubmit
//    with if-constexpr hardening. If it dies again, gload_lds is implicated.
//  - WRITE_SIZE on early dispatches includes harness memset traffic (artifact).

enum { HEPI_XP = 0, HEPI_UZ = 1, HEPI_F32 = 2, HEPI_D34 = 3 };

// ====== hgemm_g: 64-row tiles, global_load_lds staging, LDK=32 + XOR swizzle ======
// Swizzle (rule #21, both-sides): LDS granule (row r, g) holds global k-octet
// g ^ ((r>>1)&3). gload_lds writes linearly (lane l -> granule l), so lane l
// FETCHES octet kc=(l&3)^((l>>3)&3) of row 16*chunk+(l>>2); reads use the same
// XOR (lane-constant col). 16-lane read groups: 2 lanes/granule-slot -> free.
// LDS: NT=2 16KB (10 blk/CU), NT=4 24KB (6 blk/CU) -- occupancy UP vs LDK40.
template<int EPI, bool A_F32KM, int NT>
__global__ __launch_bounds__(256)
void hgemm_g(const float* __restrict__ Af0, const float* __restrict__ Af1,
             const __half* __restrict__ Ah_g, const __half* __restrict__ Bh_g,
             const float* __restrict__ bias,
             float* __restrict__ O0, __half* __restrict__ Oh0, __half* __restrict__ Oh1,
             int M, int N, int K, int kSplit, long strideAb, int nBlk)
{
    constexpr int BM = 64, MT = 2;
    constexpr int BN = 2 * NT * 16;         // 64 or 128
    constexpr int BCH = BN / 64;            // B gload instrs per wave: 1 or 2
    __shared__ __align__(16) _Float16 Ah[2][BM][32];
    __shared__ __align__(16) _Float16 Bh[2][BN][32];
    const int mBlk = M / BM;
    // XCD-sticky swizzle
    const int bid = blockIdx.x;
    const int r = bid & 7, q = bid >> 3;
    const int ni = q % nBlk;
    const int mg = (q / nBlk) * 8 + r;
    const int b = mg / mBlk, m_idx = mg - b * mBlk;
    const int n0 = ni * BN, m0 = m_idx * BM;
    const int tid  = threadIdx.x;
    const int lane = tid & 63;
    const int w    = tid >> 6;
    const int wr   = w >> 1, wc = w & 1;
    const int lrow = lane & 15;
    const int loct = lane >> 4;
    // gload source mapping: lane l -> row-in-chunk l>>2, swizzled k-octet kc
    const int gsub = lane >> 2;
    const int kc   = (lane & 3) ^ ((lane >> 3) & 3);
    // read-side swizzled column (f16 units), lane-constant
    const int swc  = (loct ^ ((lrow >> 1) & 3)) * 8;

    f32x4 acc[MT][NT];
    #pragma unroll
    for (int i = 0; i < MT; ++i)
        #pragma unroll
        for (int j = 0; j < NT; ++j)
            acc[i][j] = (f32x4){0.f, 0.f, 0.f, 0.f};

    float va[8];
    auto loadA32 = [&](int kk) {        // GEMM1: fp32 K-major A -> regs (needs cvt)
        if constexpr (A_F32KM) {
            int m = tid & 63, ks = tid >> 6;
            #pragma unroll
            for (int j = 0; j < 8; ++j) {
                int kg = kk + ks * 8 + j;
                const float* Ap; int kl;
                if (kg < kSplit) { Ap = Af0; kl = kg; } else { Ap = Af1; kl = kg - kSplit; }
                va[j] = Ap[(long)b * strideAb + (long)kl * M + m0 + m];
            }
        }
    };
    auto storeA32 = [&](int buf) {      // swizzled ds_write (matches read XOR)
        if constexpr (A_F32KM) {
            int m = tid & 63, ks = tid >> 6;
            int ksw = (ks ^ ((m >> 1) & 3)) * 8;
            uint4 h;
            h.x = pk2h(va[0], va[1]);
            h.y = pk2h(va[2], va[3]);
            h.z = pk2h(va[4], va[5]);
            h.w = pk2h(va[6], va[7]);
            *(uint4*)&Ah[buf][m][ksw] = h;
        }
    };
    auto stageA = [&](int kk, int buf) {
        if constexpr (!A_F32KM) {
            const __half* src = Ah_g + (long)b * strideAb +
                                (long)(m0 + w * 16 + gsub) * K + kk + kc * 8;
            gload_lds16(src, &Ah[buf][w * 16][0]);
        }
    };
    auto stageB = [&](int kk, int buf) {
        #pragma unroll
        for (int p = 0; p < BCH; ++p) {
            int ch = w * BCH + p;       // 16-row chunk index
            const __half* src = Bh_g + (long)(n0 + ch * 16 + gsub) * K + kk + kc * 8;
            gload_lds16(src, &Bh[buf][ch * 16][0]);
        }
    };

    loadA32(0);
    stageA(0, 0); stageB(0, 0);
    storeA32(0);
    __syncthreads();                    // drains vmcnt -> gloads landed
    int cur = 0;
    for (int kk = 0; kk < K; kk += 32) {
        const bool more = (kk + 32 < K);
        if (more) {
            loadA32(kk + 32);
            stageA(kk + 32, cur ^ 1);   // async, direct to LDS buf^1
            stageB(kk + 32, cur ^ 1);
        }
        f16x8 bh[NT];
        #pragma unroll
        for (int nt = 0; nt < NT; ++nt)
            bh[nt] = *(const f16x8*)&Bh[cur][wc*NT*16 + nt*16 + lrow][swc];
        #pragma unroll
        for (int mt = 0; mt < MT; ++mt) {
            f16x8 ah = *(const f16x8*)&Ah[cur][wr*MT*16 + mt*16 + lrow][swc];
            #pragma unroll
            for (int nt = 0; nt < NT; ++nt)
                acc[mt][nt] = __builtin_amdgcn_mfma_f32_16x16x32_f16(ah, bh[nt], acc[mt][nt], 0, 0, 0);
        }
        if (more) {
            storeA32(cur ^ 1);
            __syncthreads();            // ONE barrier per k-iter (r0 schedule)
            cur ^= 1;
        }
    }
    // epilogue: C/D col=lane&15, row=(lane>>4)*4+reg
    #pragma unroll
    for (int mt = 0; mt < MT; ++mt) {
        #pragma unroll
        for (int r4 = 0; r4 < 4; ++r4) {
            int m = m0 + wr*MT*16 + mt * 16 + loct * 4 + r4;
            long rowb = (long)b * M + m;
            #pragma unroll
            for (int nt = 0; nt < NT; ++nt) {
                int n = n0 + wc*NT*16 + nt * 16 + lrow;
                float v = acc[mt][nt][r4];
                if constexpr (EPI == HEPI_XP) {
                    Oh0[rowb * N + n] = __float2half(v + bias[n]);
                } else if constexpr (EPI == HEPI_UZ) {
                    if (n < DIN) Oh0[rowb * DIN + n] = __float2half(v);
                    else         Oh1[rowb * DIN + (n - DIN)] = __float2half(v);
                } else {
                    O0[rowb * N + n] = v;
                }
            }
        }
    }
}

#define LDK 40
// ====== old reg-staged hgemm (LDK=40): kept ONLY for D34 (needs OOB zero-guard) ===
template<int EPI, int NT>
__global__ __launch_bounds__(256)
void hgemm(const __half* __restrict__ Ah_g, const __half* __restrict__ Bh_g,
           float* __restrict__ O0, float* __restrict__ Ob, float* __restrict__ Oc,
           int M, int N, int K, long strideAb, int nBlk)
{
    constexpr int BM = 64, MT = 2;
    constexpr int BN = 2 * NT * 16;
    constexpr int BSEG = BN / 64;
    __shared__ __align__(16) _Float16 Ah[2][BM][LDK];
    __shared__ __align__(16) _Float16 Bh[2][BN][LDK];
    const int mBlk = M / BM;
    const int bid = blockIdx.x;
    const int r = bid & 7, q = bid >> 3;
    const int ni = q % nBlk;
    const int mg = (q / nBlk) * 8 + r;
    const int b = mg / mBlk, m_idx = mg - b * mBlk;
    const int n0 = ni * BN, m0 = m_idx * BM;
    const int tid  = threadIdx.x;
    const int lane = tid & 63;
    const int w    = tid >> 6;
    const int wr   = w >> 1, wc = w & 1;
    const int lrow = lane & 15;
    const int loct = lane >> 4;

    f32x4 acc[MT][NT];
    #pragma unroll
    for (int i = 0; i < MT; ++i)
        #pragma unroll
        for (int j = 0; j < NT; ++j)
            acc[i][j] = (f32x4){0.f, 0.f, 0.f, 0.f};

    const int sOct = tid & 3, sRow = tid >> 2;
    uint4 pa, pb[BSEG];

    auto loadA = [&](int kk) {
        pa = *(const uint4*)(Ah_g + (long)b * strideAb +
                             (long)(m0 + sRow) * K + kk + sOct * 8);
    };
    auto loadB = [&](int kk) {
        #pragma unroll
        for (int p = 0; p < BSEG; ++p) {
            int ng = n0 + sRow + p * 64;
            if (ng >= N) pb[p] = make_uint4(0, 0, 0, 0);
            else pb[p] = *(const uint4*)(Bh_g + (long)ng * K + kk + sOct * 8);
        }
    };
    auto storeAB = [&](int buf) {
        *(uint4*)&Ah[buf][sRow][sOct * 8] = pa;
        #pragma unroll
        for (int p = 0; p < BSEG; ++p)
            *(uint4*)&Bh[buf][sRow + p * 64][sOct * 8] = pb[p];
    };

    loadA(0); loadB(0);
    storeAB(0);
    __syncthreads();
    int cur = 0;
    for (int kk = 0; kk < K; kk += 32) {
        const bool more = (kk + 32 < K);
        if (more) { loadA(kk + 32); loadB(kk + 32); }
        f16x8 bh[NT];
        #pragma unroll
        for (int nt = 0; nt < NT; ++nt)
            bh[nt] = *(const f16x8*)&Bh[cur][wc*NT*16 + nt*16 + lrow][loct*8];
        #pragma unroll
        for (int mt = 0; mt < MT; ++mt) {
            f16x8 ah = *(const f16x8*)&Ah[cur][wr*MT*16 + mt*16 + lrow][loct*8];
            #pragma unroll
            for (int nt = 0; nt < NT; ++nt)
                acc[mt][nt] = __builtin_amdgcn_mfma_f32_16x16x32_f16(ah, bh[nt], acc[mt][nt], 0, 0, 0);
        }
        if (more) {
            storeAB(cur ^ 1);
            __syncthreads();
            cur ^= 1;
        }
    }
    #pragma unroll
    for (int mt = 0; mt < MT; ++mt) {
        #pragma unroll
        for (int r4 = 0; r4 < 4; ++r4) {
            int m = m0 + wr*MT*16 + mt * 16 + loct * 4 + r4;
            long rowb = (long)b * M + m;
            #pragma unroll
            for (int nt = 0; nt < NT; ++nt) {
                int n = n0 + wc*NT*16 + nt * 16 + lrow;
                float v = acc[mt][nt][r4];
                if (n < DTR)           O0[rowb * DTR + n] = v;
                else if (n < 2 * DTR)  Ob[rowb * 16 + (n - DTR)] = v;
                else if (n < 48)       Oc[rowb * 16 + (n - 32)] = v;
            }
        }
    }
}

// ---------------- weight prep: fp16 casts ---------
#define SZ_WP  131072
#define SZ_WIN 262144
#define SZ_WO  131072
#define SZ_WC  24576
__global__ __launch_bounds__(256)
void pack_all(const float* __restrict__ Wp, const float* __restrict__ Win,
              const float* __restrict__ Wout, const float* __restrict__ Wx,
              __half* __restrict__ wph, __half* __restrict__ winh,
              __half* __restrict__ woh, __half* __restrict__ wch)
{
    int i = blockIdx.x * 256 + threadIdx.x;
    if (i < SZ_WP) { wph[i] = __float2half(Wp[i]); return; }
    i -= SZ_WP;
    if (i < SZ_WIN) { winh[i] = __float2half(Win[i]); return; }
    i -= SZ_WIN;
    if (i < SZ_WO) { woh[i] = __float2half(Wout[i]); return; }
    i -= SZ_WO;
    if (i < SZ_WC) wch[i] = __float2half(Wx[i]);   // (48, 512) row-major
}

// ---------------- depthwise causal conv (k=4) + silu ---------
__global__ __launch_bounds__(256)
void conv_silu_kernel(const __half* __restrict__ u_pre, const float* __restrict__ cw,
                      const float* __restrict__ cb, __half* __restrict__ u)
{
    long idx = (long)blockIdx.x * blockDim.x + threadIdx.x;
    int d = (int)(idx % DIN);
    long bl = idx / DIN;
    int l = (int)(bl % L);
    long brow = bl - l;
    float v = cb[d];
    #pragma unroll
    for (int j = 0; j < 4; ++j) {
        int li = l - 3 + j;
        if (li >= 0) v += __half2float(u_pre[(brow + li) * DIN + d]) * cw[d * 4 + j];
    }
    u[idx] = __float2half(silu_f(v));
}

// ---------------- chunked parallel selective scan, d-per-lane (r6 pk-f32) --------
#define NC 128
#define LC (L / NC)

__device__ __forceinline__ f32x2 fma2(f32x2 a, f32x2 b, f32x2 c) {
    return __builtin_elementwise_fma(a, b, c);
}

__global__ __launch_bounds__(256)
void scan_phase1(const float* __restrict__ dtA, const __half* __restrict__ u,
                 const float* __restrict__ Bm, const float* __restrict__ A_log,
                 const float* __restrict__ Wdt, const float* __restrict__ bdt,
                 float* __restrict__ AX)
{
    __shared__ float sB[LC][DSTATE];
    __shared__ float sDt[LC][DTR];
    __shared__ __half sU[LC][256];
    const int gd = blockIdx.x & 1;
    const int c  = (blockIdx.x >> 1) & (NC - 1);
    const int b  = blockIdx.x >> 8;
    const int tid = threadIdx.x;
    const int d  = gd * 256 + tid;
    const int t0 = c * LC;
    f32x2 A2[8];
    #pragma unroll
    for (int q = 0; q < 4; ++q) {
        float4 v = *(const float4*)&A_log[d * DSTATE + q * 4];
        A2[2*q]   = (f32x2){-__expf(v.x) * LOG2E, -__expf(v.y) * LOG2E};
        A2[2*q+1] = (f32x2){-__expf(v.z) * LOG2E, -__expf(v.w) * LOG2E};
    }
    f32x2 Wv[8];
    #pragma unroll
    for (int q = 0; q < 4; ++q) {
        float4 v = *(const float4*)&Wdt[d * DTR + q * 4];
        Wv[2*q]   = (f32x2){v.x, v.y};
        Wv[2*q+1] = (f32x2){v.z, v.w};
    }
    const float bd = bdt[d];
    {
        const __half* ub = u + ((long)b * L + t0) * DIN + gd * 256;
        #pragma unroll
        for (int j = 0; j < 4; ++j) {
            int i = tid + j * 256;
            int t = i >> 5, col = (i & 31) * 8;
            *(float4*)&sU[t][col] = *(const float4*)&ub[(long)t * DIN + col];
        }
        if (tid < 128) {
            const float* Bb = Bm  + ((long)b * L + t0) * DSTATE;
            const float* Db = dtA + ((long)b * L + t0) * DTR;
            *(float4*)&((float*)sB)[tid * 4]  = *(const float4*)&Bb[tid * 4];
            *(float4*)&((float*)sDt)[tid * 4] = *(const float4*)&Db[tid * 4];
        }
    }
    __syncthreads();
    f32x2 X2[8];
    #pragma unroll
    for (int k = 0; k < 8; ++k) X2[k] = (f32x2){0.f, 0.f};
    float dsum = 0.f;
    #pragma unroll 2
    for (int t = 0; t < LC; ++t) {
        float qd[16], br[16];
        *(float4*)&qd[0]  = *(const float4*)&sDt[t][0];
        *(float4*)&qd[4]  = *(const float4*)&sDt[t][4];
        *(float4*)&qd[8]  = *(const float4*)&sDt[t][8];
        *(float4*)&qd[12] = *(const float4*)&sDt[t][12];
        f32x2 dpA = (f32x2){0.f, 0.f}, dpB = (f32x2){0.f, 0.f};
        #pragma unroll
        for (int k = 0; k < 8; k += 2) {
            dpA = fma2(*(const f32x2*)&qd[2*k],     Wv[k],     dpA);
            dpB = fma2(*(const f32x2*)&qd[2*k+2],   Wv[k+1],   dpB);
        }
        float dlt = softplus_fast(((dpA.x + dpA.y) + (dpB.x + dpB.y)) + bd);
        dsum += dlt;
        float du = dlt * __half2float(sU[t][tid]);
        f32x2 du2  = (f32x2){du, du};
        f32x2 dlt2 = (f32x2){dlt, dlt};
        *(float4*)&br[0]  = *(const float4*)&sB[t][0];
        *(float4*)&br[4]  = *(const float4*)&sB[t][4];
        *(float4*)&br[8]  = *(const float4*)&sB[t][8];
        *(float4*)&br[12] = *(const float4*)&sB[t][12];
        #pragma unroll
        for (int k = 0; k < 8; ++k) {
            f32x2 tt = dlt2 * A2[k];
            f32x2 a2;
            a2.x = EXP2(tt.x);
            a2.y = EXP2(tt.y);
            X2[k] = fma2(a2, X2[k], du2 * *(const f32x2*)&br[2*k]);
        }
    }
    f32x2 ds2 = (f32x2){dsum, dsum};
    long o2 = ((((long)b * NC + c) * DIN + d) * DSTATE) * 2;
    #pragma unroll
    for (int k = 0; k < 8; ++k) {
        f32x2 pt = ds2 * A2[k];
        float p0 = EXP2(pt.x), p1 = EXP2(pt.y);
        *(float4*)&AX[o2 + k * 4] = make_float4(p0, X2[k].x, p1, X2[k].y);
    }
}

// cross-chunk scan: 32768 independent series; pure-ILP kernel.
__global__ __launch_bounds__(256)
void scan_phase2(const float* __restrict__ AX, float* __restrict__ Hout)
{
    int lane = blockIdx.x * 256 + threadIdx.x;   // 32768 total
    int b = lane >> 13;
    int rem = lane & 8191;
    const long cs = (long)DIN * DSTATE;
    const long base = (long)b * NC * cs + rem;
    float h = 0.f;
    float2 c0, c1, c2, c3, n0, n1, n2, n3;
    auto ld = [&](int c) -> float2 {
        return *(const float2*)&AX[2 * (base + (long)c * cs)];
    };
    c0 = ld(0); c1 = ld(1); c2 = ld(2); c3 = ld(3);
    n0 = ld(4); n1 = ld(5); n2 = ld(6); n3 = ld(7);
    for (int c = 0; c < NC; c += 4) {
        Hout[base + (long)(c+0) * cs] = h; h = fmaf(c0.x, h, c0.y);
        Hout[base + (long)(c+1) * cs] = h; h = fmaf(c1.x, h, c1.y);
        Hout[base + (long)(c+2) * cs] = h; h = fmaf(c2.x, h, c2.y);
        Hout[base + (long)(c+3) * cs] = h; h = fmaf(c3.x, h, c3.y);
        c0 = n0; c1 = n1; c2 = n2; c3 = n3;
        if (c + 8 < NC) { n0 = ld(c+8); n1 = ld(c+9); n2 = ld(c+10); n3 = ld(c+11); }
    }
}

__global__ __launch_bounds__(256)
void scan_phase3(const float* __restrict__ dtA, const __half* __restrict__ u,
                 const float* __restrict__ Bm, const float* __restrict__ Cm,
                 const __half* __restrict__ z, const float* __restrict__ A_log,
                 const float* __restrict__ Wdt, const float* __restrict__ bdt,
                 const float* __restrict__ Dp, const float* __restrict__ Hinit,
                 __half* __restrict__ y2h)
{
    __shared__ float sB[LC][DSTATE], sC[LC][DSTATE];
    __shared__ float sDt[LC][DTR];
    __shared__ __half sU[LC][256];
    __shared__ __half sZ[LC][256];
    const int gd = blockIdx.x & 1;
    const int c  = (blockIdx.x >> 1) & (NC - 1);
    const int b  = blockIdx.x >> 8;
    const int tid = threadIdx.x;
    const int d  = gd * 256 + tid;
    const int t0 = c * LC;
    f32x2 A2[8];
    #pragma unroll
    for (int q = 0; q < 4; ++q) {
        float4 v = *(const float4*)&A_log[d * DSTATE + q * 4];
        A2[2*q]   = (f32x2){-__expf(v.x) * LOG2E, -__expf(v.y) * LOG2E};
        A2[2*q+1] = (f32x2){-__expf(v.z) * LOG2E, -__expf(v.w) * LOG2E};
    }
    f32x2 Wv[8];
    #pragma unroll
    for (int q = 0; q < 4; ++q) {
        float4 v = *(const float4*)&Wdt[d * DTR + q * 4];
        Wv[2*q]   = (f32x2){v.x, v.y};
        Wv[2*q+1] = (f32x2){v.z, v.w};
    }
    const float bd = bdt[d];
    {
        const __half* ub = u + ((long)b * L + t0) * DIN + gd * 256;
        const __half* zb = z + ((long)b * L + t0) * DIN + gd * 256;
        #pragma unroll
        for (int j = 0; j < 4; ++j) {
            int i = tid + j * 256;
            int t = i >> 5, col = (i & 31) * 8;
            *(float4*)&sU[t][col] = *(const float4*)&ub[(long)t * DIN + col];
            *(float4*)&sZ[t][col] = *(const float4*)&zb[(long)t * DIN + col];
        }
        if (tid < 128) {
            const float* Bb = Bm  + ((long)b * L + t0) * DSTATE;
            const float* Cb = Cm  + ((long)b * L + t0) * DSTATE;
            const float* Db = dtA + ((long)b * L + t0) * DTR;
            *(float4*)&((float*)sB)[tid * 4]  = *(const float4*)&Bb[tid * 4];
            *(float4*)&((float*)sC)[tid * 4]  = *(const float4*)&Cb[tid * 4];
            *(float4*)&((float*)sDt)[tid * 4] = *(const float4*)&Db[tid * 4];
        }
    }
    f32x2 h2[8];
    {
        long o = (((long)b * NC + c) * DIN + d) * DSTATE;
        #pragma unroll
        for (int q = 0; q < 4; ++q) {
            float4 v = *(const float4*)&Hinit[o + q * 4];
            h2[2*q]   = (f32x2){v.x, v.y};
            h2[2*q+1] = (f32x2){v.z, v.w};
        }
    }
    const float Dval = Dp[d];
    const long gbase = ((long)b * L + t0) * DIN + d;
    __syncthreads();
    #pragma unroll 2
    for (int t = 0; t < LC; ++t) {
        float qd[16], br[16], cr[16];
        *(float4*)&qd[0]  = *(const float4*)&sDt[t][0];
        *(float4*)&qd[4]  = *(const float4*)&sDt[t][4];
        *(float4*)&qd[8]  = *(const float4*)&sDt[t][8];
        *(float4*)&qd[12] = *(const float4*)&sDt[t][12];
        f32x2 dpA = (f32x2){0.f, 0.f}, dpB = (f32x2){0.f, 0.f};
        #pragma unroll
        for (int k = 0; k < 8; k += 2) {
            dpA = fma2(*(const f32x2*)&qd[2*k],   Wv[k],   dpA);
            dpB = fma2(*(const f32x2*)&qd[2*k+2], Wv[k+1], dpB);
        }
        float dlt = softplus_fast(((dpA.x + dpA.y) + (dpB.x + dpB.y)) + bd);
        float uu = __half2float(sU[t][tid]);
        float zz = __half2float(sZ[t][tid]);
        float du = dlt * uu;
        f32x2 du2  = (f32x2){du, du};
        f32x2 dlt2 = (f32x2){dlt, dlt};
        *(float4*)&br[0]  = *(const float4*)&sB[t][0];
        *(float4*)&br[4]  = *(const float4*)&sB[t][4];
        *(float4*)&br[8]  = *(const float4*)&sB[t][8];
        *(float4*)&br[12] = *(const float4*)&sB[t][12];
        *(float4*)&cr[0]  = *(const float4*)&sC[t][0];
        *(float4*)&cr[4]  = *(const float4*)&sC[t][4];
        *(float4*)&cr[8]  = *(const float4*)&sC[t][8];
        *(float4*)&cr[12] = *(const float4*)&sC[t][12];
        f32x2 y2a = (f32x2){0.f, 0.f}, y2b = (f32x2){0.f, 0.f};
        f32x2 y2c = (f32x2){0.f, 0.f}, y2d = (f32x2){0.f, 0.f};
        #pragma unroll
        for (int k = 0; k < 8; k += 4) {
            f32x2 t0v = dlt2 * A2[k+0];
            f32x2 t1v = dlt2 * A2[k+1];
            f32x2 t2v = dlt2 * A2[k+2];
            f32x2 t3v = dlt2 * A2[k+3];
            f32x2 a0, a1, a2v, a3;
            a0.x = EXP2(t0v.x); a0.y = EXP2(t0v.y);
            a1.x = EXP2(t1v.x); a1.y = EXP2(t1v.y);
            a2v.x = EXP2(t2v.x); a2v.y = EXP2(t2v.y);
            a3.x = EXP2(t3v.x); a3.y = EXP2(t3v.y);
            h2[k+0] = fma2(h2[k+0], a0,  du2 * *(const f32x2*)&br[2*k+0]);
            h2[k+1] = fma2(h2[k+1], a1,  du2 * *(const f32x2*)&br[2*k+2]);
            h2[k+2] = fma2(h2[k+2], a2v, du2 * *(const f32x2*)&br[2*k+4]);
            h2[k+3] = fma2(h2[k+3], a3,  du2 * *(const f32x2*)&br[2*k+6]);
            y2a = fma2(h2[k+0], *(const f32x2*)&cr[2*k+0], y2a);
            y2b = fma2(h2[k+1], *(const f32x2*)&cr[2*k+2], y2b);
            y2c = fma2(h2[k+2], *(const f32x2*)&cr[2*k+4], y2c);
            y2d = fma2(h2[k+3], *(const f32x2*)&cr[2*k+6], y2d);
        }
        f32x2 ys = (y2a + y2b) + (y2c + y2d);
        float y = ys.x + ys.y;
        y2h[gbase + t * DIN] = __float2half((y + uu * Dval) * silu_f(zz));
    }
}

// ---------------- LayerNorm over C + transpose to (B,C,L) ----------------
__global__ __launch_bounds__(256)
void ln_kernel(const float* __restrict__ X, const float* __restrict__ gamma,
               const float* __restrict__ beta, float* __restrict__ out)
{
    __shared__ float tile[32][257];
    __shared__ float sMu[32], sRs[32];
    const int l0 = blockIdx.x * 32;
    const int b  = blockIdx.y;
    const int tid = threadIdx.x;
    for (int i = tid; i < 32 * 256; i += 256) {
        int l = i >> 8, c = i & 255;
        tile[l][c] = X[((long)b * L + l0 + l) * CDIM + c];
    }
    __syncthreads();
    {
        int l = tid >> 3, sub = tid & 7;
        float s1 = 0.f, s2 = 0.f;
        for (int c = sub * 32; c < sub * 32 + 32; ++c) {
            float v = tile[l][c];
            s1 += v; s2 += v * v;
        }
        s1 += __shfl_xor(s1, 1); s2 += __shfl_xor(s2, 1);
        s1 += __shfl_xor(s1, 2); s2 += __shfl_xor(s2, 2);
        s1 += __shfl_xor(s1, 4); s2 += __shfl_xor(s2, 4);
        if (sub == 0) {
            float mu = s1 * (1.f / 256.f);
            float var = s2 * (1.f / 256.f) - mu * mu;
            sMu[l] = mu;
            sRs[l] = rsqrtf(var + 1e-5f);
        }
    }
    __syncthreads();
    for (int i = tid; i < 32 * 256; i += 256) {
        int ll = i & 31, c = i >> 5;
        float v = (tile[ll][c] - sMu[ll]) * sRs[ll] * gamma[c] + beta[c];
        out[((long)b * CDIM + c) * L + l0 + ll] = v;
    }
}

extern "C" void kernel_launch(void* const* d_in, const int* in_sizes, int n_in,
                              void* d_out, int out_size, void* d_ws, size_t ws_size,
                              hipStream_t stream)
{
    const float* sp   = (const float*)d_in[0];
    const float* fq   = (const float*)d_in[1];
    const float* Wp   = (const float*)d_in[2];
    const float* bp   = (const float*)d_in[3];
    const float* Win  = (const float*)d_in[4];
    const float* cw   = (const float*)d_in[5];
    const float* cb   = (const float*)d_in[6];
    const float* Wx   = (const float*)d_in[7];
    const float* Wdt  = (const float*)d_in[8];
    const float* bdt  = (const float*)d_in[9];
    const float* Alog = (const float*)d_in[10];
    const float* Dp   = (const float*)d_in[11];
    const float* Wout = (const float*)d_in[12];
    const float* gam  = (const float*)d_in[13];
    const float* bet  = (const float*)d_in[14];
    float* out = (float*)d_out;
    float* ws  = (float*)d_ws;

    const size_t NLD = (size_t)BATCH * L * DIN;   // 8.39M
    const size_t NLC = (size_t)BATCH * L * CDIM;  // 4.19M

    size_t off = 0;
    __half* u16   = (__half*)(ws + off); off += NLD / 2;  // pre-conv u
    __half* u16c  = (__half*)(ws + off); off += NLD / 2;  // post-conv silu(u)
    __half* z16   = (__half*)(ws + off); off += NLD / 2;
    __half* y16   = (__half*)(ws + off); off += NLD / 2;
    __half* xp16  = (__half*)(ws + off); off += NLC / 2;
    float*  xmix  = ws + off; off += NLC;
    float*  dtA   = ws + off; off += (size_t)BATCH * L * DTR;
    __half* wph   = (__half*)(ws + off); off += SZ_WP / 2;
    __half* winh  = (__half*)(ws + off); off += SZ_WIN / 2;
    __half* woh   = (__half*)(ws + off); off += SZ_WO / 2;
    __half* wch   = (__half*)(ws + off); off += SZ_WC / 2;
    float*  Bmb   = ws + off; off += (size_t)BATCH * L * DSTATE;
    float*  Cmb   = ws + off; off += (size_t)BATCH * L * DSTATE;
    float*  AX    = ws + off; off += (size_t)BATCH * NC * DIN * DSTATE * 2;
    float*  Hout  = ws + off; off += (size_t)BATCH * NC * DIN * DSTATE;

    dim3 blk(256);
    pack_all<<<dim3((SZ_WP + SZ_WIN + SZ_WO + SZ_WC) / 256), blk, 0, stream>>>(
        Wp, Win, Wout, Wx, wph, winh, woh, wch);

    // GEMM1: x_proj = x_cat @ Wp^T + bp  (A fp32 K-major reg-staged; B gload_lds)
    hgemm_g<HEPI_XP, true, 2><<<dim3(BATCH * (L/64) * 4), blk, 0, stream>>>(
        sp, fq, nullptr, wph, bp, nullptr, xp16, nullptr,
        L, CDIM, 2 * CDIM, CDIM, (long)CDIM * L, 4);
    // GEMM2: xz = x_proj @ Win^T -> u16 / z16  (full gload_lds staging)
    hgemm_g<HEPI_UZ, false, 4><<<dim3(BATCH * (L/64) * 8), blk, 0, stream>>>(
        nullptr, nullptr, xp16, winh, nullptr, nullptr, u16, z16,
        L, 2 * DIN, CDIM, 1 << 30, (long)L * CDIM, 8);

    conv_silu_kernel<<<dim3((int)(NLD / 256)), blk, 0, stream>>>(u16, cw, cb, u16c);
    // D34 rank-16: dbc = u @ Wx^T (N=48: dt|Bm|Cm) -- old kernel (OOB guard)
    hgemm<HEPI_D34, 2><<<dim3(BATCH * (L/64) * 1), blk, 0, stream>>>(
        u16c, wch, dtA, Bmb, Cmb, L, 48, DIN, (long)L * DIN, 1);

    scan_phase1<<<dim3(BATCH * NC * 2), blk, 0, stream>>>(
        dtA, u16c, Bmb, Alog, Wdt, bdt, AX);
    scan_phase2<<<dim3(BATCH * DIN * DSTATE / 256), blk, 0, stream>>>(AX, Hout);
    scan_phase3<<<dim3(BATCH * NC * 2), blk, 0, stream>>>(
        dtA, u16c, Bmb, Cmb, z16, Alog, Wdt, bdt, Dp, Hout, y16);

    // GEMM5: x_mixed = y2 @ Wout^T  (full gload_lds staging)
    hgemm_g<HEPI_F32, false, 2><<<dim3(BATCH * (L/64) * 4), blk, 0, stream>>>(
        nullptr, nullptr, y16, woh, nullptr, xmix, nullptr, nullptr,
        L, CDIM, DIN, 1 << 30, (long)L * DIN, 4);
    ln_kernel<<<dim3(L / 32, BATCH), blk, 0, stream>>>(xmix, gam, bet, out);
}

// Round 9
// 297.669 us; speedup vs baseline: 1.2082x; 1.0097x over previous
//
#include <hip/hip_runtime.h>
#include <hip/hip_fp16.h>
#include <math.h>

#define L 4096
#define CDIM 256
#define DIN 512
#define DSTATE 16
#define DTR 16
#define BATCH 4

using f32x4  = __attribute__((ext_vector_type(4))) float;
using f32x2  = __attribute__((ext_vector_type(2))) float;
using f16x8  = __attribute__((ext_vector_type(8))) _Float16;

#define LOG2E 1.44269504088896f

#if __has_builtin(__builtin_amdgcn_exp2f)
#define EXP2(x) __builtin_amdgcn_exp2f(x)
#else
#define EXP2(x) __expf((x) * 0.69314718056f)
#endif

__device__ __forceinline__ float silu_f(float x) {
    return __fdividef(x, 1.f + __expf(-x));
}
__device__ __forceinline__ float softplus_fast(float x) {
    return (x > 20.f) ? x : __logf(1.f + __expf(x));
}
__device__ __forceinline__ unsigned pk2h(float a, float b) {
    __half2 h = __floats2half2_rn(a, b);
    return *reinterpret_cast<unsigned*>(&h);
}

// async global->LDS, 16B per lane, dest = wave-uniform base + lane*16
__device__ __forceinline__ void gload_lds16(const void* g, void* l) {
    __builtin_amdgcn_global_load_lds(
        (const __attribute__((address_space(1))) void*)g,
        (__attribute__((address_space(3))) void*)l, 16, 0, 0);
}

// LESSONS (measured, do not repeat):
//  - r1: lgkm-only barrier + depth-2 reg prefetch regressed (6.6->4.4 MfmaUtil).
//  - r4: GEMM1+GEMM2 fusion neutral (stall-bound; blocks x k-iters unchanged).
//  - r4: replacing 16 exp2 (trans pipe, hidden under VALU) with 15 serial VALU
//    muls REGRESSED scans ~+23us. Delete VALU ops, keep trans ops.
//  - r5: 128x128 tile regressed GEMMs: occupancy hides stalls here; 64-tile wins.
//  - r6: pk-f32 (f32x2) scan math WORKED: scans left the top-5. 320.1us.
//  - r7: infra flake (container died in setup); r8 resubmit passed.
//  - r8: gload_lds + LDK32 swizzle WORKED: GEMMs left top-5. 300.6us.
//  - WRITE_SIZE on early dispatches includes harness memset traffic (artifact).

enum { HEPI_XP = 0, HEPI_UZ = 1, HEPI_F32 = 2, HEPI_D34 = 3 };

// ====== hgemm_g: 64-row tiles, global_load_lds staging, LDK=32 + XOR swizzle ======
// Swizzle (rule #21, both-sides): LDS granule (row r, g) holds global k-octet
// g ^ ((r>>1)&3). gload_lds writes linearly (lane l -> granule l), so lane l
// FETCHES octet kc=(l&3)^((l>>3)&3) of row 16*chunk+(l>>2); reads use the same
// XOR (lane-constant col). 16-lane read groups: 2 lanes/granule-slot -> free.
template<int EPI, bool A_F32KM, int NT>
__global__ __launch_bounds__(256)
void hgemm_g(const float* __restrict__ Af0, const float* __restrict__ Af1,
             const __half* __restrict__ Ah_g, const __half* __restrict__ Bh_g,
             const float* __restrict__ bias,
             float* __restrict__ O0, __half* __restrict__ Oh0, __half* __restrict__ Oh1,
             int M, int N, int K, int kSplit, long strideAb, int nBlk)
{
    constexpr int BM = 64, MT = 2;
    constexpr int BN = 2 * NT * 16;         // 64 or 128
    constexpr int BCH = BN / 64;            // B gload instrs per wave: 1 or 2
    __shared__ __align__(16) _Float16 Ah[2][BM][32];
    __shared__ __align__(16) _Float16 Bh[2][BN][32];
    const int mBlk = M / BM;
    // XCD-sticky swizzle
    const int bid = blockIdx.x;
    const int r = bid & 7, q = bid >> 3;
    const int ni = q % nBlk;
    const int mg = (q / nBlk) * 8 + r;
    const int b = mg / mBlk, m_idx = mg - b * mBlk;
    const int n0 = ni * BN, m0 = m_idx * BM;
    const int tid  = threadIdx.x;
    const int lane = tid & 63;
    const int w    = tid >> 6;
    const int wr   = w >> 1, wc = w & 1;
    const int lrow = lane & 15;
    const int loct = lane >> 4;
    // gload source mapping: lane l -> row-in-chunk l>>2, swizzled k-octet kc
    const int gsub = lane >> 2;
    const int kc   = (lane & 3) ^ ((lane >> 3) & 3);
    // read-side swizzled column (f16 units), lane-constant
    const int swc  = (loct ^ ((lrow >> 1) & 3)) * 8;

    f32x4 acc[MT][NT];
    #pragma unroll
    for (int i = 0; i < MT; ++i)
        #pragma unroll
        for (int j = 0; j < NT; ++j)
            acc[i][j] = (f32x4){0.f, 0.f, 0.f, 0.f};

    float va[8];
    auto loadA32 = [&](int kk) {        // GEMM1: fp32 K-major A -> regs (needs cvt)
        if constexpr (A_F32KM) {
            int m = tid & 63, ks = tid >> 6;
            #pragma unroll
            for (int j = 0; j < 8; ++j) {
                int kg = kk + ks * 8 + j;
                const float* Ap; int kl;
                if (kg < kSplit) { Ap = Af0; kl = kg; } else { Ap = Af1; kl = kg - kSplit; }
                va[j] = Ap[(long)b * strideAb + (long)kl * M + m0 + m];
            }
        }
    };
    auto storeA32 = [&](int buf) {      // swizzled ds_write (matches read XOR)
        if constexpr (A_F32KM) {
            int m = tid & 63, ks = tid >> 6;
            int ksw = (ks ^ ((m >> 1) & 3)) * 8;
            uint4 h;
            h.x = pk2h(va[0], va[1]);
            h.y = pk2h(va[2], va[3]);
            h.z = pk2h(va[4], va[5]);
            h.w = pk2h(va[6], va[7]);
            *(uint4*)&Ah[buf][m][ksw] = h;
        }
    };
    auto stageA = [&](int kk, int buf) {
        if constexpr (!A_F32KM) {
            const __half* src = Ah_g + (long)b * strideAb +
                                (long)(m0 + w * 16 + gsub) * K + kk + kc * 8;
            gload_lds16(src, &Ah[buf][w * 16][0]);
        }
    };
    auto stageB = [&](int kk, int buf) {
        #pragma unroll
        for (int p = 0; p < BCH; ++p) {
            int ch = w * BCH + p;       // 16-row chunk index
            const __half* src = Bh_g + (long)(n0 + ch * 16 + gsub) * K + kk + kc * 8;
            gload_lds16(src, &Bh[buf][ch * 16][0]);
        }
    };

    loadA32(0);
    stageA(0, 0); stageB(0, 0);
    storeA32(0);
    __syncthreads();                    // drains vmcnt -> gloads landed
    int cur = 0;
    for (int kk = 0; kk < K; kk += 32) {
        const bool more = (kk + 32 < K);
        if (more) {
            loadA32(kk + 32);
            stageA(kk + 32, cur ^ 1);   // async, direct to LDS buf^1
            stageB(kk + 32, cur ^ 1);
        }
        f16x8 bh[NT];
        #pragma unroll
        for (int nt = 0; nt < NT; ++nt)
            bh[nt] = *(const f16x8*)&Bh[cur][wc*NT*16 + nt*16 + lrow][swc];
        #pragma unroll
        for (int mt = 0; mt < MT; ++mt) {
            f16x8 ah = *(const f16x8*)&Ah[cur][wr*MT*16 + mt*16 + lrow][swc];
            #pragma unroll
            for (int nt = 0; nt < NT; ++nt)
                acc[mt][nt] = __builtin_amdgcn_mfma_f32_16x16x32_f16(ah, bh[nt], acc[mt][nt], 0, 0, 0);
        }
        if (more) {
            storeA32(cur ^ 1);
            __syncthreads();            // ONE barrier per k-iter (r0 schedule)
            cur ^= 1;
        }
    }
    // epilogue: C/D col=lane&15, row=(lane>>4)*4+reg
    #pragma unroll
    for (int mt = 0; mt < MT; ++mt) {
        #pragma unroll
        for (int r4 = 0; r4 < 4; ++r4) {
            int m = m0 + wr*MT*16 + mt * 16 + loct * 4 + r4;
            long rowb = (long)b * M + m;
            #pragma unroll
            for (int nt = 0; nt < NT; ++nt) {
                int n = n0 + wc*NT*16 + nt * 16 + lrow;
                float v = acc[mt][nt][r4];
                if constexpr (EPI == HEPI_XP) {
                    Oh0[rowb * N + n] = __float2half(v + bias[n]);
                } else if constexpr (EPI == HEPI_UZ) {
                    if (n < DIN) Oh0[rowb * DIN + n] = __float2half(v);
                    else         Oh1[rowb * DIN + (n - DIN)] = __float2half(v);
                } else {
                    O0[rowb * N + n] = v;
                }
            }
        }
    }
}

#define LDK 40
// ====== old reg-staged hgemm (LDK=40): kept ONLY for D34 (needs OOB zero-guard) ===
template<int EPI, int NT>
__global__ __launch_bounds__(256)
void hgemm(const __half* __restrict__ Ah_g, const __half* __restrict__ Bh_g,
           float* __restrict__ O0, float* __restrict__ Ob, float* __restrict__ Oc,
           int M, int N, int K, long strideAb, int nBlk)
{
    constexpr int BM = 64, MT = 2;
    constexpr int BN = 2 * NT * 16;
    constexpr int BSEG = BN / 64;
    __shared__ __align__(16) _Float16 Ah[2][BM][LDK];
    __shared__ __align__(16) _Float16 Bh[2][BN][LDK];
    const int mBlk = M / BM;
    const int bid = blockIdx.x;
    const int r = bid & 7, q = bid >> 3;
    const int ni = q % nBlk;
    const int mg = (q / nBlk) * 8 + r;
    const int b = mg / mBlk, m_idx = mg - b * mBlk;
    const int n0 = ni * BN, m0 = m_idx * BM;
    const int tid  = threadIdx.x;
    const int lane = tid & 63;
    const int w    = tid >> 6;
    const int wr   = w >> 1, wc = w & 1;
    const int lrow = lane & 15;
    const int loct = lane >> 4;

    f32x4 acc[MT][NT];
    #pragma unroll
    for (int i = 0; i < MT; ++i)
        #pragma unroll
        for (int j = 0; j < NT; ++j)
            acc[i][j] = (f32x4){0.f, 0.f, 0.f, 0.f};

    const int sOct = tid & 3, sRow = tid >> 2;
    uint4 pa, pb[BSEG];

    auto loadA = [&](int kk) {
        pa = *(const uint4*)(Ah_g + (long)b * strideAb +
                             (long)(m0 + sRow) * K + kk + sOct * 8);
    };
    auto loadB = [&](int kk) {
        #pragma unroll
        for (int p = 0; p < BSEG; ++p) {
            int ng = n0 + sRow + p * 64;
            if (ng >= N) pb[p] = make_uint4(0, 0, 0, 0);
            else pb[p] = *(const uint4*)(Bh_g + (long)ng * K + kk + sOct * 8);
        }
    };
    auto storeAB = [&](int buf) {
        *(uint4*)&Ah[buf][sRow][sOct * 8] = pa;
        #pragma unroll
        for (int p = 0; p < BSEG; ++p)
            *(uint4*)&Bh[buf][sRow + p * 64][sOct * 8] = pb[p];
    };

    loadA(0); loadB(0);
    storeAB(0);
    __syncthreads();
    int cur = 0;
    for (int kk = 0; kk < K; kk += 32) {
        const bool more = (kk + 32 < K);
        if (more) { loadA(kk + 32); loadB(kk + 32); }
        f16x8 bh[NT];
        #pragma unroll
        for (int nt = 0; nt < NT; ++nt)
            bh[nt] = *(const f16x8*)&Bh[cur][wc*NT*16 + nt*16 + lrow][loct*8];
        #pragma unroll
        for (int mt = 0; mt < MT; ++mt) {
            f16x8 ah = *(const f16x8*)&Ah[cur][wr*MT*16 + mt*16 + lrow][loct*8];
            #pragma unroll
            for (int nt = 0; nt < NT; ++nt)
                acc[mt][nt] = __builtin_amdgcn_mfma_f32_16x16x32_f16(ah, bh[nt], acc[mt][nt], 0, 0, 0);
        }
        if (more) {
            storeAB(cur ^ 1);
            __syncthreads();
            cur ^= 1;
        }
    }
    #pragma unroll
    for (int mt = 0; mt < MT; ++mt) {
        #pragma unroll
        for (int r4 = 0; r4 < 4; ++r4) {
            int m = m0 + wr*MT*16 + mt * 16 + loct * 4 + r4;
            long rowb = (long)b * M + m;
            #pragma unroll
            for (int nt = 0; nt < NT; ++nt) {
                int n = n0 + wc*NT*16 + nt * 16 + lrow;
                float v = acc[mt][nt][r4];
                if (n < DTR)           O0[rowb * DTR + n] = v;
                else if (n < 2 * DTR)  Ob[rowb * 16 + (n - DTR)] = v;
                else if (n < 48)       Oc[rowb * 16 + (n - 32)] = v;
            }
        }
    }
}

// ---------------- weight prep: fp16 casts ---------
#define SZ_WP  131072
#define SZ_WIN 262144
#define SZ_WO  131072
#define SZ_WC  24576
__global__ __launch_bounds__(256)
void pack_all(const float* __restrict__ Wp, const float* __restrict__ Win,
              const float* __restrict__ Wout, const float* __restrict__ Wx,
              __half* __restrict__ wph, __half* __restrict__ winh,
              __half* __restrict__ woh, __half* __restrict__ wch)
{
    int i = blockIdx.x * 256 + threadIdx.x;
    if (i < SZ_WP) { wph[i] = __float2half(Wp[i]); return; }
    i -= SZ_WP;
    if (i < SZ_WIN) { winh[i] = __float2half(Win[i]); return; }
    i -= SZ_WIN;
    if (i < SZ_WO) { woh[i] = __float2half(Wout[i]); return; }
    i -= SZ_WO;
    if (i < SZ_WC) wch[i] = __float2half(Wx[i]);   // (48, 512) row-major
}

// ------- depthwise causal conv (k=4) + silu: VECTORIZED 8 d's/thread (G13) -------
__global__ __launch_bounds__(256)
void conv_silu_kernel(const __half* __restrict__ u_pre, const float* __restrict__ cw,
                      const float* __restrict__ cb, __half* __restrict__ u)
{
    long gid = (long)blockIdx.x * 256 + threadIdx.x;   // NLD/8 threads
    const int dv = (int)(gid & 63);                    // d0 = dv*8
    const long bl = gid >> 6;                          // b*L + l
    const int l = (int)(bl & (L - 1));
    const long brow = bl - l;
    const int d0 = dv * 8;

    float acc[8];
    {
        float4 c0 = *(const float4*)&cb[d0];
        float4 c1 = *(const float4*)&cb[d0 + 4];
        acc[0]=c0.x; acc[1]=c0.y; acc[2]=c0.z; acc[3]=c0.w;
        acc[4]=c1.x; acc[5]=c1.y; acc[6]=c1.z; acc[7]=c1.w;
    }
    float4 wrow[8];                                    // cw rows (hot 8KB in L2)
    #pragma unroll
    for (int e = 0; e < 8; ++e) wrow[e] = *(const float4*)&cw[(d0 + e) * 4];

    #pragma unroll
    for (int j = 0; j < 4; ++j) {
        int li = l - 3 + j;                            // wave-uniform branch
        if (li >= 0) {
            uint4 raw = *(const uint4*)(u_pre + (brow + li) * DIN + d0);
            const __half2* h2 = (const __half2*)&raw;
            #pragma unroll
            for (int e = 0; e < 4; ++e) {
                float2 f = __half22float2(h2[e]);
                float w0 = (j == 0) ? wrow[2*e].x : (j == 1) ? wrow[2*e].y
                         : (j == 2) ? wrow[2*e].z : wrow[2*e].w;
                float w1 = (j == 0) ? wrow[2*e+1].x : (j == 1) ? wrow[2*e+1].y
                         : (j == 2) ? wrow[2*e+1].z : wrow[2*e+1].w;
                acc[2*e]   = fmaf(f.x, w0, acc[2*e]);
                acc[2*e+1] = fmaf(f.y, w1, acc[2*e+1]);
            }
        }
    }
    uint4 st;
    st.x = pk2h(silu_f(acc[0]), silu_f(acc[1]));
    st.y = pk2h(silu_f(acc[2]), silu_f(acc[3]));
    st.z = pk2h(silu_f(acc[4]), silu_f(acc[5]));
    st.w = pk2h(silu_f(acc[6]), silu_f(acc[7]));
    *(uint4*)(u + bl * DIN + d0) = st;
}

// ---------------- chunked parallel selective scan, d-per-lane (r6 pk-f32) --------
// r9: phase1 stores X[16] + dsum only (P dropped); phase2 recomputes
// P = exp2(dsum*Ar) on the fly (latency-bound kernel, spare trans slots).
// Cuts AX traffic 33.5 -> 17.8 MB each way.
#define NC 128
#define LC (L / NC)

__device__ __forceinline__ f32x2 fma2(f32x2 a, f32x2 b, f32x2 c) {
    return __builtin_elementwise_fma(a, b, c);
}

__global__ __launch_bounds__(256)
void scan_phase1(const float* __restrict__ dtA, const __half* __restrict__ u,
                 const float* __restrict__ Bm, const float* __restrict__ A_log,
                 const float* __restrict__ Wdt, const float* __restrict__ bdt,
                 float* __restrict__ Xc, float* __restrict__ DS)
{
    __shared__ float sB[LC][DSTATE];
    __shared__ float sDt[LC][DTR];
    __shared__ __half sU[LC][256];
    const int gd = blockIdx.x & 1;
    const int c  = (blockIdx.x >> 1) & (NC - 1);
    const int b  = blockIdx.x >> 8;
    const int tid = threadIdx.x;
    const int d  = gd * 256 + tid;
    const int t0 = c * LC;
    f32x2 A2[8];
    #pragma unroll
    for (int q = 0; q < 4; ++q) {
        float4 v = *(const float4*)&A_log[d * DSTATE + q * 4];
        A2[2*q]   = (f32x2){-__expf(v.x) * LOG2E, -__expf(v.y) * LOG2E};
        A2[2*q+1] = (f32x2){-__expf(v.z) * LOG2E, -__expf(v.w) * LOG2E};
    }
    f32x2 Wv[8];
    #pragma unroll
    for (int q = 0; q < 4; ++q) {
        float4 v = *(const float4*)&Wdt[d * DTR + q * 4];
        Wv[2*q]   = (f32x2){v.x, v.y};
        Wv[2*q+1] = (f32x2){v.z, v.w};
    }
    const float bd = bdt[d];
    {
        const __half* ub = u + ((long)b * L + t0) * DIN + gd * 256;
        #pragma unroll
        for (int j = 0; j < 4; ++j) {
            int i = tid + j * 256;
            int t = i >> 5, col = (i & 31) * 8;
            *(float4*)&sU[t][col] = *(const float4*)&ub[(long)t * DIN + col];
        }
        if (tid < 128) {
            const float* Bb = Bm  + ((long)b * L + t0) * DSTATE;
            const float* Db = dtA + ((long)b * L + t0) * DTR;
            *(float4*)&((float*)sB)[tid * 4]  = *(const float4*)&Bb[tid * 4];
            *(float4*)&((float*)sDt)[tid * 4] = *(const float4*)&Db[tid * 4];
        }
    }
    __syncthreads();
    f32x2 X2[8];
    #pragma unroll
    for (int k = 0; k < 8; ++k) X2[k] = (f32x2){0.f, 0.f};
    float dsum = 0.f;
    #pragma unroll 2
    for (int t = 0; t < LC; ++t) {
        float qd[16], br[16];
        *(float4*)&qd[0]  = *(const float4*)&sDt[t][0];
        *(float4*)&qd[4]  = *(const float4*)&sDt[t][4];
        *(float4*)&qd[8]  = *(const float4*)&sDt[t][8];
        *(float4*)&qd[12] = *(const float4*)&sDt[t][12];
        f32x2 dpA = (f32x2){0.f, 0.f}, dpB = (f32x2){0.f, 0.f};
        #pragma unroll
        for (int k = 0; k < 8; k += 2) {
            dpA = fma2(*(const f32x2*)&qd[2*k],     Wv[k],     dpA);
            dpB = fma2(*(const f32x2*)&qd[2*k+2],   Wv[k+1],   dpB);
        }
        float dlt = softplus_fast(((dpA.x + dpA.y) + (dpB.x + dpB.y)) + bd);
        dsum += dlt;
        float du = dlt * __half2float(sU[t][tid]);
        f32x2 du2  = (f32x2){du, du};
        f32x2 dlt2 = (f32x2){dlt, dlt};
        *(float4*)&br[0]  = *(const float4*)&sB[t][0];
        *(float4*)&br[4]  = *(const float4*)&sB[t][4];
        *(float4*)&br[8]  = *(const float4*)&sB[t][8];
        *(float4*)&br[12] = *(const float4*)&sB[t][12];
        #pragma unroll
        for (int k = 0; k < 8; ++k) {
            f32x2 tt = dlt2 * A2[k];
            f32x2 a2;
            a2.x = EXP2(tt.x);
            a2.y = EXP2(tt.y);
            X2[k] = fma2(a2, X2[k], du2 * *(const f32x2*)&br[2*k]);
        }
    }
    long o = (((long)b * NC + c) * DIN + d) * DSTATE;
    #pragma unroll
    for (int q = 0; q < 4; ++q)
        *(float4*)&Xc[o + q * 4] =
            make_float4(X2[2*q].x, X2[2*q].y, X2[2*q+1].x, X2[2*q+1].y);
    DS[((long)b * NC + c) * DIN + d] = dsum;
}

// cross-chunk scan: 32768 independent series; pure-ILP kernel.
// P recomputed as exp2(dsum*Ar): halves the per-chunk load traffic.
__global__ __launch_bounds__(256)
void scan_phase2(const float* __restrict__ Xc, const float* __restrict__ DS,
                 const float* __restrict__ A_log, float* __restrict__ Hout)
{
    int lane = blockIdx.x * 256 + threadIdx.x;   // 32768 total
    int b = lane >> 13;
    int rem = lane & 8191;                       // d*16 + s
    int d = rem >> 4;
    const float Ar = -__expf(A_log[rem]) * LOG2E;
    const long cs = (long)DIN * DSTATE;
    const long xb = (long)b * NC * cs + rem;
    const long db = (long)b * NC * DIN + d;
    float h = 0.f;
    float x0, x1, x2, x3, t0, t1, t2, t3;
    float nx0, nx1, nx2, nx3, nt0, nt1, nt2, nt3;
    auto ldx = [&](int c) { return Xc[xb + (long)c * cs]; };
    auto ldt = [&](int c) { return DS[db + (long)c * DIN]; };
    x0 = ldx(0); x1 = ldx(1); x2 = ldx(2); x3 = ldx(3);
    t0 = ldt(0); t1 = ldt(1); t2 = ldt(2); t3 = ldt(3);
    nx0 = ldx(4); nx1 = ldx(5); nx2 = ldx(6); nx3 = ldx(7);
    nt0 = ldt(4); nt1 = ldt(5); nt2 = ldt(6); nt3 = ldt(7);
    for (int c = 0; c < NC; c += 4) {
        float P0 = EXP2(t0 * Ar), P1 = EXP2(t1 * Ar);
        float P2 = EXP2(t2 * Ar), P3 = EXP2(t3 * Ar);
        Hout[xb + (long)(c+0) * cs] = h; h = fmaf(P0, h, x0);
        Hout[xb + (long)(c+1) * cs] = h; h = fmaf(P1, h, x1);
        Hout[xb + (long)(c+2) * cs] = h; h = fmaf(P2, h, x2);
        Hout[xb + (long)(c+3) * cs] = h; h = fmaf(P3, h, x3);
        x0 = nx0; x1 = nx1; x2 = nx2; x3 = nx3;
        t0 = nt0; t1 = nt1; t2 = nt2; t3 = nt3;
        if (c + 8 < NC) {
            nx0 = ldx(c+8); nx1 = ldx(c+9); nx2 = ldx(c+10); nx3 = ldx(c+11);
            nt0 = ldt(c+8); nt1 = ldt(c+9); nt2 = ldt(c+10); nt3 = ldt(c+11);
        }
    }
}

__global__ __launch_bounds__(256)
void scan_phase3(const float* __restrict__ dtA, const __half* __restrict__ u,
                 const float* __restrict__ Bm, const float* __restrict__ Cm,
                 const __half* __restrict__ z, const float* __restrict__ A_log,
                 const float* __restrict__ Wdt, const float* __restrict__ bdt,
                 const float* __restrict__ Dp, const float* __restrict__ Hinit,
                 __half* __restrict__ y2h)
{
    __shared__ float sB[LC][DSTATE], sC[LC][DSTATE];
    __shared__ float sDt[LC][DTR];
    __shared__ __half sU[LC][256];
    __shared__ __half sZ[LC][256];
    const int gd = blockIdx.x & 1;
    const int c  = (blockIdx.x >> 1) & (NC - 1);
    const int b  = blockIdx.x >> 8;
    const int tid = threadIdx.x;
    const int d  = gd * 256 + tid;
    const int t0 = c * LC;
    f32x2 A2[8];
    #pragma unroll
    for (int q = 0; q < 4; ++q) {
        float4 v = *(const float4*)&A_log[d * DSTATE + q * 4];
        A2[2*q]   = (f32x2){-__expf(v.x) * LOG2E, -__expf(v.y) * LOG2E};
        A2[2*q+1] = (f32x2){-__expf(v.z) * LOG2E, -__expf(v.w) * LOG2E};
    }
    f32x2 Wv[8];
    #pragma unroll
    for (int q = 0; q < 4; ++q) {
        float4 v = *(const float4*)&Wdt[d * DTR + q * 4];
        Wv[2*q]   = (f32x2){v.x, v.y};
        Wv[2*q+1] = (f32x2){v.z, v.w};
    }
    const float bd = bdt[d];
    {
        const __half* ub = u + ((long)b * L + t0) * DIN + gd * 256;
        const __half* zb = z + ((long)b * L + t0) * DIN + gd * 256;
        #pragma unroll
        for (int j = 0; j < 4; ++j) {
            int i = tid + j * 256;
            int t = i >> 5, col = (i & 31) * 8;
            *(float4*)&sU[t][col] = *(const float4*)&ub[(long)t * DIN + col];
            *(float4*)&sZ[t][col] = *(const float4*)&zb[(long)t * DIN + col];
        }
        if (tid < 128) {
            const float* Bb = Bm  + ((long)b * L + t0) * DSTATE;
            const float* Cb = Cm  + ((long)b * L + t0) * DSTATE;
            const float* Db = dtA + ((long)b * L + t0) * DTR;
            *(float4*)&((float*)sB)[tid * 4]  = *(const float4*)&Bb[tid * 4];
            *(float4*)&((float*)sC)[tid * 4]  = *(const float4*)&Cb[tid * 4];
            *(float4*)&((float*)sDt)[tid * 4] = *(const float4*)&Db[tid * 4];
        }
    }
    f32x2 h2[8];
    {
        long o = (((long)b * NC + c) * DIN + d) * DSTATE;
        #pragma unroll
        for (int q = 0; q < 4; ++q) {
            float4 v = *(const float4*)&Hinit[o + q * 4];
            h2[2*q]   = (f32x2){v.x, v.y};
            h2[2*q+1] = (f32x2){v.z, v.w};
        }
    }
    const float Dval = Dp[d];
    const long gbase = ((long)b * L + t0) * DIN + d;
    __syncthreads();
    #pragma unroll 2
    for (int t = 0; t < LC; ++t) {
        float qd[16], br[16], cr[16];
        *(float4*)&qd[0]  = *(const float4*)&sDt[t][0];
        *(float4*)&qd[4]  = *(const float4*)&sDt[t][4];
        *(float4*)&qd[8]  = *(const float4*)&sDt[t][8];
        *(float4*)&qd[12] = *(const float4*)&sDt[t][12];
        f32x2 dpA = (f32x2){0.f, 0.f}, dpB = (f32x2){0.f, 0.f};
        #pragma unroll
        for (int k = 0; k < 8; k += 2) {
            dpA = fma2(*(const f32x2*)&qd[2*k],   Wv[k],   dpA);
            dpB = fma2(*(const f32x2*)&qd[2*k+2], Wv[k+1], dpB);
        }
        float dlt = softplus_fast(((dpA.x + dpA.y) + (dpB.x + dpB.y)) + bd);
        float uu = __half2float(sU[t][tid]);
        float zz = __half2float(sZ[t][tid]);
        float du = dlt * uu;
        f32x2 du2  = (f32x2){du, du};
        f32x2 dlt2 = (f32x2){dlt, dlt};
        *(float4*)&br[0]  = *(const float4*)&sB[t][0];
        *(float4*)&br[4]  = *(const float4*)&sB[t][4];
        *(float4*)&br[8]  = *(const float4*)&sB[t][8];
        *(float4*)&br[12] = *(const float4*)&sB[t][12];
        *(float4*)&cr[0]  = *(const float4*)&sC[t][0];
        *(float4*)&cr[4]  = *(const float4*)&sC[t][4];
        *(float4*)&cr[8]  = *(const float4*)&sC[t][8];
        *(float4*)&cr[12] = *(const float4*)&sC[t][12];
        f32x2 y2a = (f32x2){0.f, 0.f}, y2b = (f32x2){0.f, 0.f};
        f32x2 y2c = (f32x2){0.f, 0.f}, y2d = (f32x2){0.f, 0.f};
        #pragma unroll
        for (int k = 0; k < 8; k += 4) {
            f32x2 t0v = dlt2 * A2[k+0];
            f32x2 t1v = dlt2 * A2[k+1];
            f32x2 t2v = dlt2 * A2[k+2];
            f32x2 t3v = dlt2 * A2[k+3];
            f32x2 a0, a1, a2v, a3;
            a0.x = EXP2(t0v.x); a0.y = EXP2(t0v.y);
            a1.x = EXP2(t1v.x); a1.y = EXP2(t1v.y);
            a2v.x = EXP2(t2v.x); a2v.y = EXP2(t2v.y);
            a3.x = EXP2(t3v.x); a3.y = EXP2(t3v.y);
            h2[k+0] = fma2(h2[k+0], a0,  du2 * *(const f32x2*)&br[2*k+0]);
            h2[k+1] = fma2(h2[k+1], a1,  du2 * *(const f32x2*)&br[2*k+2]);
            h2[k+2] = fma2(h2[k+2], a2v, du2 * *(const f32x2*)&br[2*k+4]);
            h2[k+3] = fma2(h2[k+3], a3,  du2 * *(const f32x2*)&br[2*k+6]);
            y2a = fma2(h2[k+0], *(const f32x2*)&cr[2*k+0], y2a);
            y2b = fma2(h2[k+1], *(const f32x2*)&cr[2*k+2], y2b);
            y2c = fma2(h2[k+2], *(const f32x2*)&cr[2*k+4], y2c);
            y2d = fma2(h2[k+3], *(const f32x2*)&cr[2*k+6], y2d);
        }
        f32x2 ys = (y2a + y2b) + (y2c + y2d);
        float y = ys.x + ys.y;
        y2h[gbase + t * DIN] = __float2half((y + uu * Dval) * silu_f(zz));
    }
}

// ---------------- LayerNorm over C + transpose to (B,C,L) ----------------
__global__ __launch_bounds__(256)
void ln_kernel(const float* __restrict__ X, const float* __restrict__ gamma,
               const float* __restrict__ beta, float* __restrict__ out)
{
    __shared__ float tile[32][257];
    __shared__ float sMu[32], sRs[32];
    const int l0 = blockIdx.x * 32;
    const int b  = blockIdx.y;
    const int tid = threadIdx.x;
    for (int i = tid; i < 32 * 256; i += 256) {
        int l = i >> 8, c = i & 255;
        tile[l][c] = X[((long)b * L + l0 + l) * CDIM + c];
    }
    __syncthreads();
    {
        int l = tid >> 3, sub = tid & 7;
        float s1 = 0.f, s2 = 0.f;
        for (int c = sub * 32; c < sub * 32 + 32; ++c) {
            float v = tile[l][c];
            s1 += v; s2 += v * v;
        }
        s1 += __shfl_xor(s1, 1); s2 += __shfl_xor(s2, 1);
        s1 += __shfl_xor(s1, 2); s2 += __shfl_xor(s2, 2);
        s1 += __shfl_xor(s1, 4); s2 += __shfl_xor(s2, 4);
        if (sub == 0) {
            float mu = s1 * (1.f / 256.f);
            float var = s2 * (1.f / 256.f) - mu * mu;
            sMu[l] = mu;
            sRs[l] = rsqrtf(var + 1e-5f);
        }
    }
    __syncthreads();
    for (int i = tid; i < 32 * 256; i += 256) {
        int ll = i & 31, c = i >> 5;
        float v = (tile[ll][c] - sMu[ll]) * sRs[ll] * gamma[c] + beta[c];
        out[((long)b * CDIM + c) * L + l0 + ll] = v;
    }
}

extern "C" void kernel_launch(void* const* d_in, const int* in_sizes, int n_in,
                              void* d_out, int out_size, void* d_ws, size_t ws_size,
                              hipStream_t stream)
{
    const float* sp   = (const float*)d_in[0];
    const float* fq   = (const float*)d_in[1];
    const float* Wp   = (const float*)d_in[2];
    const float* bp   = (const float*)d_in[3];
    const float* Win  = (const float*)d_in[4];
    const float* cw   = (const float*)d_in[5];
    const float* cb   = (const float*)d_in[6];
    const float* Wx   = (const float*)d_in[7];
    const float* Wdt  = (const float*)d_in[8];
    const float* bdt  = (const float*)d_in[9];
    const float* Alog = (const float*)d_in[10];
    const float* Dp   = (const float*)d_in[11];
    const float* Wout = (const float*)d_in[12];
    const float* gam  = (const float*)d_in[13];
    const float* bet  = (const float*)d_in[14];
    float* out = (float*)d_out;
    float* ws  = (float*)d_ws;

    const size_t NLD = (size_t)BATCH * L * DIN;   // 8.39M
    const size_t NLC = (size_t)BATCH * L * CDIM;  // 4.19M

    size_t off = 0;
    __half* u16   = (__half*)(ws + off); off += NLD / 2;  // pre-conv u
    __half* u16c  = (__half*)(ws + off); off += NLD / 2;  // post-conv silu(u)
    __half* z16   = (__half*)(ws + off); off += NLD / 2;
    __half* y16   = (__half*)(ws + off); off += NLD / 2;
    __half* xp16  = (__half*)(ws + off); off += NLC / 2;
    float*  xmix  = ws + off; off += NLC;
    float*  dtA   = ws + off; off += (size_t)BATCH * L * DTR;
    __half* wph   = (__half*)(ws + off); off += SZ_WP / 2;
    __half* winh  = (__half*)(ws + off); off += SZ_WIN / 2;
    __half* woh   = (__half*)(ws + off); off += SZ_WO / 2;
    __half* wch   = (__half*)(ws + off); off += SZ_WC / 2;
    float*  Bmb   = ws + off; off += (size_t)BATCH * L * DSTATE;
    float*  Cmb   = ws + off; off += (size_t)BATCH * L * DSTATE;
    float*  Xc    = ws + off; off += (size_t)BATCH * NC * DIN * DSTATE;
    float*  DS    = ws + off; off += (size_t)BATCH * NC * DIN;
    float*  Hout  = ws + off; off += (size_t)BATCH * NC * DIN * DSTATE;

    dim3 blk(256);
    pack_all<<<dim3((SZ_WP + SZ_WIN + SZ_WO + SZ_WC) / 256), blk, 0, stream>>>(
        Wp, Win, Wout, Wx, wph, winh, woh, wch);

    // GEMM1: x_proj = x_cat @ Wp^T + bp  (A fp32 K-major reg-staged; B gload_lds)
    hgemm_g<HEPI_XP, true, 2><<<dim3(BATCH * (L/64) * 4), blk, 0, stream>>>(
        sp, fq, nullptr, wph, bp, nullptr, xp16, nullptr,
        L, CDIM, 2 * CDIM, CDIM, (long)CDIM * L, 4);
    // GEMM2: xz = x_proj @ Win^T -> u16 / z16  (full gload_lds staging)
    hgemm_g<HEPI_UZ, false, 4><<<dim3(BATCH * (L/64) * 8), blk, 0, stream>>>(
        nullptr, nullptr, xp16, winh, nullptr, nullptr, u16, z16,
        L, 2 * DIN, CDIM, 1 << 30, (long)L * CDIM, 8);

    conv_silu_kernel<<<dim3((int)(NLD / 8 / 256)), blk, 0, stream>>>(u16, cw, cb, u16c);
    // D34 rank-16: dbc = u @ Wx^T (N=48: dt|Bm|Cm) -- old kernel (OOB guard)
    hgemm<HEPI_D34, 2><<<dim3(BATCH * (L/64) * 1), blk, 0, stream>>>(
        u16c, wch, dtA, Bmb, Cmb, L, 48, DIN, (long)L * DIN, 1);

    scan_phase1<<<dim3(BATCH * NC * 2), blk, 0, stream>>>(
        dtA, u16c, Bmb, Alog, Wdt, bdt, Xc, DS);
    scan_phase2<<<dim3(BATCH * DIN * DSTATE / 256), blk, 0, stream>>>(Xc, DS, Alog, Hout);
    scan_phase3<<<dim3(BATCH * NC * 2), blk, 0, stream>>>(
        dtA, u16c, Bmb, Cmb, z16, Alog, Wdt, bdt, Dp, Hout, y16);

    // GEMM5: x_mixed = y2 @ Wout^T  (full gload_lds staging)
    hgemm_g<HEPI_F32, false, 2><<<dim3(BATCH * (L/64) * 4), blk, 0, stream>>>(
        nullptr, nullptr, y16, woh, nullptr, xmix, nullptr, nullptr,
        L, CDIM, DIN, 1 << 30, (long)L * DIN, 4);
    ln_kernel<<<dim3(L / 32, BATCH), blk, 0, stream>>>(xmix, gam, bet, out);
}